// Round 8
// baseline (369.946 us; speedup 1.0000x reference)
//
#include <hip/hip_runtime.h>
#include <hip/hip_bf16.h>
#include <math.h>

#define H 8
#define D 128
#define HID 1024
#define KCONV 4

typedef __bf16 bhalf;
typedef __bf16 bhalf4 __attribute__((ext_vector_type(4)));
typedef __bf16 bhalf8 __attribute__((ext_vector_type(8)));
typedef float f32x4 __attribute__((ext_vector_type(4)));
typedef _Float16 hlf;
typedef _Float16 half8 __attribute__((ext_vector_type(8)));
typedef _Float16 half4v __attribute__((ext_vector_type(4)));

// ---- async global->LDS (direct-to-shared DMA, bypasses VGPRs) ----
__device__ __forceinline__ void async16(const void* g, void* l) {
    __builtin_amdgcn_global_load_lds(
        (const __attribute__((address_space(1))) void*)g,
        (__attribute__((address_space(3))) void*)l, 16, 0, 0);
}

// ---------------- bf16 MFMA GEMM: C[M,N] = A[M,K]*B[N,K]^T ----------------
// 128x128 tile, BK=32, 256 threads (4 waves, 2x2 of 64x64), 16 gload_lds/step.
__global__ __launch_bounds__(256) void gemm_bf16_nt(const bhalf* A, const bhalf* B,
                                                    void* Cv,
                                                    int M, int N, int K,
                                                    int lda, int ldb, int ldc, int epi,
                                                    const float* __restrict__ A_log,
                                                    const float* __restrict__ dt_bias,
                                                    const bhalf* A2, const bhalf* B2,
                                                    void* C2, int epi2,
                                                    bhalf* __restrict__ pXAG,
                                                    float* __restrict__ pBETA)
{
    if (blockIdx.z) { A = A2; B = B2; Cv = C2; epi = epi2; }
    __shared__ __align__(16) bhalf As[128][32];   // 8 KB
    __shared__ __align__(16) bhalf Bs[128][32];   // 8 KB
    int tid = threadIdx.x;
    int wid = tid >> 6, lane = tid & 63;
    int rowBase = blockIdx.y * 128;
    int colBase = blockIdx.x * 128;
    int wm = wid >> 1, wn = wid & 1;

    f32x4 acc[4][4] = {};

    int r = lane >> 2;          // 16 rows per 1KB instr
    int cseg = lane & 3;        // 16B segment within 64B row

    for (int k0 = 0; k0 < K; k0 += 32) {
        __syncthreads();
#pragma unroll
        for (int s = 0; s < 4; ++s) {
            int j = wid * 4 + s;            // 16 instrs: 8 A + 8 B
            if (j < 8) {
                const bhalf* ga = A + (size_t)(rowBase + j * 16 + r) * lda + k0 + cseg * 8;
                async16(ga, &As[j * 16][0]);
            } else {
                int jb = j - 8;
                const bhalf* ga = B + (size_t)(colBase + jb * 16 + r) * ldb + k0 + cseg * 8;
                async16(ga, &Bs[jb * 16][0]);
            }
        }
        __syncthreads();
        int mq = lane & 15, kq = (lane >> 4) * 8;
        bhalf8 af[4], bfr[4];
#pragma unroll
        for (int mt = 0; mt < 4; ++mt)
            af[mt] = *(const bhalf8*)&As[wm * 64 + mt * 16 + mq][kq];
#pragma unroll
        for (int nt = 0; nt < 4; ++nt)
            bfr[nt] = *(const bhalf8*)&Bs[wn * 64 + nt * 16 + mq][kq];
#pragma unroll
        for (int mt = 0; mt < 4; ++mt)
#pragma unroll
            for (int nt = 0; nt < 4; ++nt)
                acc[mt][nt] = __builtin_amdgcn_mfma_f32_16x16x32_bf16(
                    af[mt], bfr[nt], acc[mt][nt], 0, 0, 0);
    }
    int rquad = (lane >> 4) * 4;
#pragma unroll
    for (int mt = 0; mt < 4; ++mt) {
        int m0 = rowBase + wm * 64 + mt * 16 + rquad;
#pragma unroll
        for (int nt = 0; nt < 4; ++nt) {
            int c = colBase + wn * 64 + (lane & 15) + nt * 16;
#pragma unroll
            for (int rr = 0; rr < 4; ++rr) {
                float val = acc[mt][nt][rr];
                int m = m0 + rr;
                if (epi == 0) {
                    ((float*)Cv)[(size_t)m * ldc + c] = val;
                } else if (epi == 1) {
                    int h = c >> 7, d = c & 127;
                    float z = val + dt_bias[h * D + d];
                    float sp = (z > 20.f) ? z : log1pf(expf(z));
                    ((float*)Cv)[(size_t)m * ldc + c] = expf(-expf(A_log[h]) * sp);
                } else if (epi == 2) {
                    ((bhalf*)Cv)[(size_t)m * ldc + c] = (bhalf)val;
                } else {
                    if (c < 3072) {
                        ((float*)Cv)[(size_t)m * 3072 + c] = val;
                    } else if (c < 3328) {
                        pXAG[(size_t)m * 256 + (c - 3072)] = (bhalf)val;
                    } else if (c < 3336) {
                        pBETA[(size_t)m * 8 + (c - 3328)] = 1.f / (1.f + expf(-val));
                    }
                }
            }
        }
    }
}

// ---------------- casts (vectorized, 4 elems/thread) ----------------
__global__ void cast1(const float* __restrict__ s, bhalf* __restrict__ d, int n4)
{
    int i = blockIdx.x * blockDim.x + threadIdx.x;
    if (i >= n4) return;
    float4 v = ((const float4*)s)[i];
    bhalf4 o = {(bhalf)v.x, (bhalf)v.y, (bhalf)v.z, (bhalf)v.w};
    ((bhalf4*)d)[i] = o;
}
__global__ void cast4(const float* __restrict__ s0, const float* __restrict__ s1,
                      const float* __restrict__ s2, const float* __restrict__ s3,
                      bhalf* __restrict__ d0, bhalf* __restrict__ d1,
                      bhalf* __restrict__ d2, bhalf* __restrict__ d3, int n4)
{
    int i = blockIdx.x * blockDim.x + threadIdx.x;
    if (i >= n4) return;
    int a = blockIdx.y;
    const float* s = (a == 0) ? s0 : (a == 1) ? s1 : (a == 2) ? s2 : s3;
    bhalf* d = (a == 0) ? d0 : (a == 1) ? d1 : (a == 2) ? d2 : d3;
    float4 v = ((const float4*)s)[i];
    bhalf4 o = {(bhalf)v.x, (bhalf)v.y, (bhalf)v.z, (bhalf)v.w};
    ((bhalf4*)d)[i] = o;
}

// ------- fused depthwise causal conv (K=4) + SiLU (+ rmsnorm*scale) --------
__global__ __launch_bounds__(128) void conv3_kernel(const float* __restrict__ QKV,
                                                    const float* __restrict__ wq,
                                                    const float* __restrict__ wk,
                                                    const float* __restrict__ wv,
                                                    float* __restrict__ Qc,
                                                    float* __restrict__ Kc,
                                                    float* __restrict__ Vc,
                                                    int T)
{
    int which = blockIdx.y;
    const float* w; float* out; int mode; float scale;
    if (which == 0)      { w = wq; out = Qc; mode = 1; scale = 1.0f / 128.0f; }
    else if (which == 1) { w = wk; out = Kc; mode = 1; scale = 0.08838834764831845f; }
    else                 { w = wv; out = Vc; mode = 0; scale = 1.f; }

    int bid = blockIdx.x;
    int h = bid % H;
    int t = (bid / H) % T;
    int b = bid / (H * T);
    int d = threadIdx.x;
    int c = h * D + d;
    const float* base = QKV + (size_t)b * T * 3072 + which * 1024 + c;
    float acc = 0.f;
#pragma unroll
    for (int j = 0; j < KCONV; ++j) {
        int tt = t - (KCONV - 1) + j;
        float xv = (tt >= 0) ? base[(size_t)tt * 3072] : 0.f;
        acc += xv * w[c * KCONV + j];
    }
    float y = acc / (1.f + expf(-acc));
    if (mode) {
        __shared__ float red[2];
        float ss = y * y;
#pragma unroll
        for (int s = 32; s > 0; s >>= 1) ss += __shfl_xor(ss, s, 64);
        if ((threadIdx.x & 63) == 0) red[threadIdx.x >> 6] = ss;
        __syncthreads();
        float tot = red[0] + red[1];
        float r = rsqrtf(tot * (1.f / D) + 1e-6f);
        y = y * r * scale;
    }
    out[(size_t)bid * D + d] = y;
}

// ---------------- DPP wave64 reduction ----------------
template <int CTRL>
__device__ __forceinline__ float dpp_add(float x) {
    int y = __builtin_amdgcn_update_dpp(0, __builtin_bit_cast(int, x),
                                        CTRL, 0xF, 0xF, false);
    return x + __builtin_bit_cast(float, y);
}
// after this chain the full-wave sum is valid in lane 63
__device__ __forceinline__ float wave_sum63(float x) {
    x = dpp_add<0x111>(x);   // row_shr:1
    x = dpp_add<0x112>(x);   // row_shr:2
    x = dpp_add<0x114>(x);   // row_shr:4
    x = dpp_add<0x118>(x);   // row_shr:8
    x = dpp_add<0x142>(x);   // row_bcast:15
    x = dpp_add<0x143>(x);   // row_bcast:31
    return x;
}

// =======================================================================
// Chunked gated-delta-rule (WY / UT-transform), chunk C = 32.
//   A_i[d]   = prod_{s<=i} e_s          suff_i[d]= prod_{s>i} e_s
//   R_ij[d]  = prod_{j<s<=i} e_s        (walked iteratively; all <=1)
//   P_ij  = sum_d k_i k_j R_ij  (i>j)   Ao_ij = sum_d q_i k_j R_ij (i>=j)
//   (I + diag(b) tril(P)) Delta = b*(V - Ktil S),  Ktil_i = k_i*A_i
//   O = Qtil S + tril(Ao) Delta;  S <- diag(A_end) S + Kbar^T Delta
// =======================================================================

// ---- pass 1: fully parallel per (bh, chunk). fp32 compute, f16 out. ----
// V staged through U_s; phase-3 reductions batched x4 (independent DPP
// chains pipeline; values bitwise identical).
__global__ __launch_bounds__(256) void chunk_prep_kernel(
    const float* __restrict__ Q, const float* __restrict__ K,
    const float* __restrict__ V, const float* __restrict__ E,
    const float* __restrict__ BETA,
    hlf* __restrict__ Wn, float* __restrict__ Uf, hlf* __restrict__ Qt,
    hlf* __restrict__ AoL, hlf* __restrict__ KbT, float* __restrict__ Aend,
    int T)
{
    __shared__ __align__(16) float e_s[32][128];   // 16K
    __shared__ __align__(16) float k_s[32][128];   // 16K
    __shared__ __align__(16) float U_s[32][128];   // 16K (V staged, then U)
    __shared__ __align__(16) hlf  A_s[32][128];    // 8K
    __shared__ __align__(16) hlf  W_s[32][128];    // 8K
    __shared__ float P_s[32][32];                  // 4K (beta-folded L)
    __shared__ float Ao_s[32][32];                 // 4K
    __shared__ float beta_s[32];

    int tid = threadIdx.x, wid = tid >> 6, lane = tid & 63;
    int bid = blockIdx.x;
    int bh = bid >> 5, ch = bid & 31;
    int b = bh >> 3, h = bh & 7;
    int t0 = ch * 32;
    size_t rowb = (size_t)(b * T + t0) * 1024 + h * 128;
    size_t co = (size_t)bh * 32 + ch;

    // ---- stage e,k,v (32 rows x 512B each; 1 async16 covers 2 rows) ----
    int rs2 = lane >> 5, seg = (lane & 31) * 4;
#pragma unroll
    for (int p = wid * 4; p < wid * 4 + 4; ++p) {
        int row = p * 2 + rs2;
        async16(E + rowb + (size_t)row * 1024 + seg, &e_s[p * 2][0]);
        async16(K + rowb + (size_t)row * 1024 + seg, &k_s[p * 2][0]);
        async16(V + rowb + (size_t)row * 1024 + seg, &U_s[p * 2][0]);
    }
    __syncthreads();

    // ---- phase 2: zero Ao, beta, cumulative products ----
    for (int x = tid; x < 1024; x += 256) Ao_s[x >> 5][x & 31] = 0.f;
    if (wid == 2 && lane < 32)
        beta_s[lane] = BETA[(size_t)(b * T + t0 + lane) * 8 + h];
    int d0 = lane * 2;
    if (wid == 0) {             // forward cumprod -> A_s, A_end
        float a0 = 1.f, a1 = 1.f;
        for (int t = 0; t < 32; ++t) {
            a0 *= e_s[t][d0]; a1 *= e_s[t][d0 + 1];
            A_s[t][d0] = (hlf)a0; A_s[t][d0 + 1] = (hlf)a1;
        }
        Aend[co * 128 + d0] = a0; Aend[co * 128 + d0 + 1] = a1;
    } else if (wid == 1) {      // backward suffix -> Kbar^T [d][t]
        float s0 = 1.f, s1 = 1.f;
        for (int t = 31; t >= 0; --t) {
            KbT[co * 4096 + (size_t)d0 * 32 + t]       = (hlf)(k_s[t][d0] * s0);
            KbT[co * 4096 + (size_t)(d0 + 1) * 32 + t] = (hlf)(k_s[t][d0 + 1] * s1);
            s0 *= e_s[t][d0]; s1 *= e_s[t][d0 + 1];
        }
    }
    __syncthreads();

    // ---- phase 3: P / Ao pairwise-decay triangle walk (j batched x4) ----
#pragma unroll
    for (int ii = 0; ii < 8; ++ii) {
        int i = wid + ii * 4;
        float ki0 = k_s[i][d0], ki1 = k_s[i][d0 + 1];
        float2 qv = *(const float2*)(Q + rowb + (size_t)i * 1024 + d0);
        float aa = wave_sum63(qv.x * ki0 + qv.y * ki1);
        if (lane == 63) Ao_s[i][i] = aa;           // diag: R = 1
        float R0 = 1.f, R1 = 1.f;
        int j = i - 1;
        for (; j >= 3; j -= 4) {
            float Ra0 = R0 * e_s[j + 1][d0],  Ra1 = R1 * e_s[j + 1][d0 + 1];
            float Rb0 = Ra0 * e_s[j][d0],     Rb1 = Ra1 * e_s[j][d0 + 1];
            float Rc0 = Rb0 * e_s[j - 1][d0], Rc1 = Rb1 * e_s[j - 1][d0 + 1];
            float Rd0 = Rc0 * e_s[j - 2][d0], Rd1 = Rc1 * e_s[j - 2][d0 + 1];
            float ua0 = Ra0 * k_s[j][d0],     ua1 = Ra1 * k_s[j][d0 + 1];
            float ub0 = Rb0 * k_s[j - 1][d0], ub1 = Rb1 * k_s[j - 1][d0 + 1];
            float uc0 = Rc0 * k_s[j - 2][d0], uc1 = Rc1 * k_s[j - 2][d0 + 1];
            float ud0 = Rd0 * k_s[j - 3][d0], ud1 = Rd1 * k_s[j - 3][d0 + 1];
            float p0 = wave_sum63(ki0 * ua0 + ki1 * ua1);
            float p1 = wave_sum63(ki0 * ub0 + ki1 * ub1);
            float p2 = wave_sum63(ki0 * uc0 + ki1 * uc1);
            float p3 = wave_sum63(ki0 * ud0 + ki1 * ud1);
            float a0 = wave_sum63(qv.x * ua0 + qv.y * ua1);
            float a1 = wave_sum63(qv.x * ub0 + qv.y * ub1);
            float a2 = wave_sum63(qv.x * uc0 + qv.y * uc1);
            float a3 = wave_sum63(qv.x * ud0 + qv.y * ud1);
            if (lane == 63) {
                P_s[i][j]     = p0; Ao_s[i][j]     = a0;
                P_s[i][j - 1] = p1; Ao_s[i][j - 1] = a1;
                P_s[i][j - 2] = p2; Ao_s[i][j - 2] = a2;
                P_s[i][j - 3] = p3; Ao_s[i][j - 3] = a3;
            }
            R0 = Rd0; R1 = Rd1;
        }
        for (; j >= 0; --j) {
            R0 *= e_s[j + 1][d0]; R1 *= e_s[j + 1][d0 + 1];
            float u0 = R0 * k_s[j][d0], u1 = R1 * k_s[j][d0 + 1];
            float pp = wave_sum63(ki0 * u0 + ki1 * u1);
            float a2 = wave_sum63(qv.x * u0 + qv.y * u1);
            if (lane == 63) { P_s[i][j] = pp; Ao_s[i][j] = a2; }
        }
    }
    __syncthreads();

    // ---- phase 4: fold beta into strict-lower L ----
    for (int x = tid; x < 1024; x += 256) {
        int i2 = x >> 5, j2 = x & 31;
        P_s[i2][j2] = (j2 < i2) ? P_s[i2][j2] * beta_s[i2] : 0.f;
    }
    __syncthreads();

    // ---- phase 5: (I+L)W = b*Ktil (wave0), (I+L)U = b*V (wave1), Qtil ----
    if (wid == 0) {
        for (int i = 0; i < 32; ++i) {
            float bb = beta_s[i];
            float a0 = bb * k_s[i][d0] * (float)A_s[i][d0];
            float a1 = bb * k_s[i][d0 + 1] * (float)A_s[i][d0 + 1];
            for (int k2 = 0; k2 < i; ++k2) {
                float L = P_s[i][k2];
                a0 -= L * (float)W_s[k2][d0];
                a1 -= L * (float)W_s[k2][d0 + 1];
            }
            W_s[i][d0] = (hlf)a0; W_s[i][d0 + 1] = (hlf)a1;
        }
    } else if (wid == 1) {
        for (int i = 0; i < 32; ++i) {
            float bb = beta_s[i];
            float2 vv = *(const float2*)&U_s[i][d0];   // staged V (LDS)
            float a0 = bb * vv.x, a1 = bb * vv.y;
            for (int k2 = 0; k2 < i; ++k2) {
                float L = P_s[i][k2];
                a0 -= L * U_s[k2][d0];
                a1 -= L * U_s[k2][d0 + 1];
            }
            U_s[i][d0] = a0; U_s[i][d0 + 1] = a1;      // overwrite V with U
        }
    } else {
        for (int r2 = wid - 2; r2 < 32; r2 += 2) {
            float2 qv = *(const float2*)(Q + rowb + (size_t)r2 * 1024 + d0);
            Qt[co * 4096 + (size_t)r2 * 128 + d0]     = (hlf)(qv.x * (float)A_s[r2][d0]);
            Qt[co * 4096 + (size_t)r2 * 128 + d0 + 1] = (hlf)(qv.y * (float)A_s[r2][d0 + 1]);
        }
    }
    __syncthreads();

    // ---- phase 6: dumps ----
    for (int x = tid; x < 4096; x += 256) {
        Wn[co * 4096 + x] = (hlf)(-(float)W_s[x >> 7][x & 127]);
        Uf[co * 4096 + x] = U_s[x >> 7][x & 127];
    }
    for (int x = tid; x < 1024; x += 256)
        AoL[co * 1024 + x] = (hlf)Ao_s[x >> 5][x & 31];
}

// ---- pass 2: serial chunk scan. S in registers; global loads are volatile
// asm, DEPTH-2 rotation with uniform robust wait vmcnt(21). Qtil@S MFMAs
// hoisted before barrier1 (no Dt dependency) to hide the Dt ds_write.
struct ScanOps {
    half8 aw0, aw1, aw2, aw3;
    half8 aq0, aq1, aq2, aq3;
    half8 bK0, bK1, bK2, bK3;
    half8 aA;
    float u0, u1, u2, u3;
    f32x4 ae0, ae1, ae2, ae3;
};

#define GLOAD16(dst, ptr) \
    asm volatile("global_load_dwordx4 %0, %1, off" : "=v"(dst) : "v"(ptr))
#define GLOAD4(dst, ptr) \
    asm volatile("global_load_dword %0, %1, off" : "=v"(dst) : "v"(ptr))

#define SCAN_WAIT21(o) \
    asm volatile("s_waitcnt vmcnt(21)" \
        : "+v"(o.aw0), "+v"(o.aw1), "+v"(o.aw2), "+v"(o.aw3), \
          "+v"(o.aq0), "+v"(o.aq1), "+v"(o.aq2), "+v"(o.aq3), \
          "+v"(o.aA), \
          "+v"(o.bK0), "+v"(o.bK1), "+v"(o.bK2), "+v"(o.bK3), \
          "+v"(o.u0), "+v"(o.u1), "+v"(o.u2), "+v"(o.u3), \
          "+v"(o.ae0), "+v"(o.ae1), "+v"(o.ae2), "+v"(o.ae3))

__device__ __forceinline__ void scan_load(ScanOps& o, size_t co,
    const hlf* __restrict__ Wn, const float* __restrict__ Uf,
    const hlf* __restrict__ Qt, const hlf* __restrict__ Ao,
    const hlf* __restrict__ KbT, const float* __restrict__ Aend,
    int tr, int vc, int dseg, int mq, int kq, int rq, int v0)
{
    const hlf*   Wc  = Wn  + co * 4096;
    const hlf*   Qc  = Qt  + co * 4096;
    const hlf*   Aoc = Ao  + co * 1024;
    const hlf*   Kbc = KbT + co * 4096;
    const float* Uc  = Uf  + co * 4096;
    const float* Aec = Aend + co * 128;
    size_t rw = (size_t)(tr + mq) * 128 + kq;
    GLOAD16(o.aw0, &Wc[rw]);
    GLOAD16(o.aw1, &Wc[rw + 32]);
    GLOAD16(o.aw2, &Wc[rw + 64]);
    GLOAD16(o.aw3, &Wc[rw + 96]);
    GLOAD16(o.aq0, &Qc[rw]);
    GLOAD16(o.aq1, &Qc[rw + 32]);
    GLOAD16(o.aq2, &Qc[rw + 64]);
    GLOAD16(o.aq3, &Qc[rw + 96]);
    GLOAD16(o.aA,  &Aoc[(tr + mq) * 32 + kq]);
    GLOAD16(o.bK0, &Kbc[(size_t)(dseg + mq) * 32 + kq]);
    GLOAD16(o.bK1, &Kbc[(size_t)(dseg + 16 + mq) * 32 + kq]);
    GLOAD16(o.bK2, &Kbc[(size_t)(dseg + 32 + mq) * 32 + kq]);
    GLOAD16(o.bK3, &Kbc[(size_t)(dseg + 48 + mq) * 32 + kq]);
    size_t ru = (size_t)(tr + rq) * 128 + v0 + vc + mq;
    GLOAD4(o.u0, &Uc[ru]);
    GLOAD4(o.u1, &Uc[ru + 128]);
    GLOAD4(o.u2, &Uc[ru + 256]);
    GLOAD4(o.u3, &Uc[ru + 384]);
    GLOAD16(o.ae0, &Aec[dseg + rq]);
    GLOAD16(o.ae1, &Aec[dseg + 16 + rq]);
    GLOAD16(o.ae2, &Aec[dseg + 32 + rq]);
    GLOAD16(o.ae3, &Aec[dseg + 48 + rq]);
}

__device__ __forceinline__ void scan_body(const ScanOps& o, int c,
    f32x4* sreg, hlf (*Sh)[136], hlf (*Dt)[40], float* __restrict__ O,
    int b, int h, int v0s, int T, int Mrows,
    int tr, int vc, int vtile, int dseg, int mq, int kq, int rq)
{
    // Sh reads (shared between Delta and O phases; held in regs across bar1)
    half8 bs0 = *(const half8*)&Sh[vc + mq][kq];
    half8 bs1 = *(const half8*)&Sh[vc + mq][32 + kq];
    half8 bs2 = *(const half8*)&Sh[vc + mq][64 + kq];
    half8 bs3 = *(const half8*)&Sh[vc + mq][96 + kq];

    // ---- Delta = U + (-W) @ S ----
    f32x4 dacc = {o.u0, o.u1, o.u2, o.u3};
    dacc = __builtin_amdgcn_mfma_f32_16x16x32_f16(o.aw0, bs0, dacc, 0, 0, 0);
    dacc = __builtin_amdgcn_mfma_f32_16x16x32_f16(o.aw1, bs1, dacc, 0, 0, 0);
    dacc = __builtin_amdgcn_mfma_f32_16x16x32_f16(o.aw2, bs2, dacc, 0, 0, 0);
    dacc = __builtin_amdgcn_mfma_f32_16x16x32_f16(o.aw3, bs3, dacc, 0, 0, 0);
    half4v dh4 = {(hlf)dacc[0], (hlf)dacc[1], (hlf)dacc[2], (hlf)dacc[3]};
    *(half4v*)&Dt[vc + mq][tr + rq] = dh4;

    // ---- O partial: Qtil @ S (no Dt dependency -> hides Dt ds_write) ----
    f32x4 oacc = {0.f, 0.f, 0.f, 0.f};
    oacc = __builtin_amdgcn_mfma_f32_16x16x32_f16(o.aq0, bs0, oacc, 0, 0, 0);
    oacc = __builtin_amdgcn_mfma_f32_16x16x32_f16(o.aq1, bs1, oacc, 0, 0, 0);
    oacc = __builtin_amdgcn_mfma_f32_16x16x32_f16(o.aq2, bs2, oacc, 0, 0, 0);
    oacc = __builtin_amdgcn_mfma_f32_16x16x32_f16(o.aq3, bs3, oacc, 0, 0, 0);

    asm volatile("s_waitcnt lgkmcnt(0)" ::: "memory");
    __builtin_amdgcn_s_barrier();
    __builtin_amdgcn_sched_barrier(0);

    // ---- O += Ao @ Delta ----
    half8 bD = *(const half8*)&Dt[vc + mq][kq];
    oacc = __builtin_amdgcn_mfma_f32_16x16x32_f16(o.aA, bD, oacc, 0, 0, 0);
    // O split per v-slice: O4[vs][bt][h][32] -- no cross-XCD line sharing
    size_t ob = (size_t)v0s * Mrows * 256 +
                ((size_t)(b * T + c * 32 + tr + rq) * 8 + h) * 32 + vc + mq;
    O[ob]       = oacc[0];
    O[ob + 256] = oacc[1];
    O[ob + 512] = oacc[2];
    O[ob + 768] = oacc[3];

    // ---- S' = diag(Aend)*S + Kbar^T @ Delta, C[m=d][n=v] (register state) ----
    half8 aD = *(const half8*)&Dt[vtile + mq][kq];
    f32x4 s0 = sreg[0] * o.ae0;
    f32x4 s1 = sreg[1] * o.ae1;
    f32x4 s2 = sreg[2] * o.ae2;
    f32x4 s3 = sreg[3] * o.ae3;
    s0 = __builtin_amdgcn_mfma_f32_16x16x32_f16(o.bK0, aD, s0, 0, 0, 0);
    s1 = __builtin_amdgcn_mfma_f32_16x16x32_f16(o.bK1, aD, s1, 0, 0, 0);
    s2 = __builtin_amdgcn_mfma_f32_16x16x32_f16(o.bK2, aD, s2, 0, 0, 0);
    s3 = __builtin_amdgcn_mfma_f32_16x16x32_f16(o.bK3, aD, s3, 0, 0, 0);
    sreg[0] = s0; sreg[1] = s1; sreg[2] = s2; sreg[3] = s3;
    {   // f16 operand copy, vector half4 writes (4 consecutive d at fixed v)
        half4v h0 = {(hlf)s0[0], (hlf)s0[1], (hlf)s0[2], (hlf)s0[3]};
        half4v h1 = {(hlf)s1[0], (hlf)s1[1], (hlf)s1[2], (hlf)s1[3]};
        half4v h2 = {(hlf)s2[0], (hlf)s2[1], (hlf)s2[2], (hlf)s2[3]};
        half4v h3 = {(hlf)s3[0], (hlf)s3[1], (hlf)s3[2], (hlf)s3[3]};
        *(half4v*)&Sh[vtile + mq][dseg + rq]      = h0;
        *(half4v*)&Sh[vtile + mq][dseg + 16 + rq] = h1;
        *(half4v*)&Sh[vtile + mq][dseg + 32 + rq] = h2;
        *(half4v*)&Sh[vtile + mq][dseg + 48 + rq] = h3;
    }
    asm volatile("s_waitcnt lgkmcnt(0)" ::: "memory");
    __builtin_amdgcn_s_barrier();
    __builtin_amdgcn_sched_barrier(0);
}

// grid = nbh*4 (bh-major: the 4 v-splits of one bh land on the same XCD).
__global__ __launch_bounds__(256, 1) void chunk_scan_kernel(
    const hlf* __restrict__ Wn, const float* __restrict__ Uf,
    const hlf* __restrict__ Qt, const hlf* __restrict__ Ao,
    const hlf* __restrict__ KbT, const float* __restrict__ Aend,
    float* __restrict__ O, int T)
{
    __shared__ __align__(16) hlf  Sh[32][136];   // f16 S copy for MFMA B-reads
    __shared__ __align__(16) hlf  Dt[32][40];    // Delta^T [v][t] f16

    int tid = threadIdx.x, wid = tid >> 6, lane = tid & 63;
    int nbh = gridDim.x >> 2;
    int bh = blockIdx.x % nbh, vs = blockIdx.x / nbh;
    int b = bh >> 3, h = bh & 7;
    int v0 = vs * 32;
    int Mrows = (nbh >> 3) * T;

    for (int x = tid; x < 32 * 136; x += 256) ((hlf*)Sh)[x] = (hlf)0.f;

    int mq = lane & 15, kq = (lane >> 4) * 8, rq = (lane >> 4) * 4;
    int tr = (wid >> 1) * 16, vc = (wid & 1) * 16;      // Delta/O tile
    int vtile = (wid >> 1) * 16, dseg = (wid & 1) * 64; // S-update tiles

    f32x4 sreg[4] = {};   // S[d][v] register master (C[m=d][n=v] fragments)

    int NC = T / 32;
    size_t cb = (size_t)bh * 32;
    size_t comax = (size_t)nbh * 32 - 1;   // clamp for tail prefetches

    // barrier WITHOUT vmcnt drain (raw s_barrier; Sh init is DS -> lgkm only)
    asm volatile("s_waitcnt lgkmcnt(0)" ::: "memory");
    __builtin_amdgcn_s_barrier();

    ScanOps op0, op1;
    scan_load(op0, cb,     Wn, Uf, Qt, Ao, KbT, Aend, tr, vc, dseg, mq, kq, rq, v0);
    scan_load(op1, cb + 1, Wn, Uf, Qt, Ao, KbT, Aend, tr, vc, dseg, mq, kq, rq, v0);

#define CCLAMP(x) ((x) > comax ? comax : (x))
    for (int cc = 0; cc < NC; cc += 2) {
        SCAN_WAIT21(op0);
        scan_body(op0, cc, sreg, Sh, Dt, O, b, h, vs, T, Mrows,
                  tr, vc, vtile, dseg, mq, kq, rq);
        scan_load(op0, CCLAMP(cb + cc + 2), Wn, Uf, Qt, Ao, KbT, Aend,
                  tr, vc, dseg, mq, kq, rq, v0);

        SCAN_WAIT21(op1);
        scan_body(op1, cc + 1, sreg, Sh, Dt, O, b, h, vs, T, Mrows,
                  tr, vc, vtile, dseg, mq, kq, rq);
        scan_load(op1, CCLAMP(cb + cc + 3), Wn, Uf, Qt, Ao, KbT, Aend,
                  tr, vc, dseg, mq, kq, rq, v0);
    }
#undef CCLAMP
}

// -------- out = rmsnorm(o)*w*sigmoid(gate) -> bf16 (for final MFMA GEMM) ----
// O is the 4-way v-split layout: O4[vs][bt][h][32]
__global__ __launch_bounds__(128) void outnorm_kernel(const float* __restrict__ O,
                                                      const float* __restrict__ GATE,
                                                      const float* __restrict__ w,
                                                      bhalf* __restrict__ Obf,
                                                      int Mrows)
{
    int bid = blockIdx.x;
    int d = threadIdx.x;
    size_t base = (size_t)bid * D;
    float y = O[(size_t)(d >> 5) * Mrows * 256 + (size_t)bid * 32 + (d & 31)];
    __shared__ float red[2];
    float ss = y * y;
#pragma unroll
    for (int s = 32; s > 0; s >>= 1) ss += __shfl_xor(ss, s, 64);
    if ((threadIdx.x & 63) == 0) red[threadIdx.x >> 6] = ss;
    __syncthreads();
    float tot = red[0] + red[1];
    float r = rsqrtf(tot * (1.f / D) + 1e-5f);
    float gz = GATE[base + d];
    float sg = 1.f / (1.f + expf(-gz));
    Obf[base + d] = (bhalf)(y * r * w[d] * sg);
}

extern "C" void kernel_launch(void* const* d_in, const int* in_sizes, int n_in,
                              void* d_out, int out_size, void* d_ws, size_t ws_size,
                              hipStream_t stream)
{
    const float* x       = (const float*)d_in[0];
    const float* Wq      = (const float*)d_in[1];
    const float* Wk      = (const float*)d_in[2];
    const float* Wv      = (const float*)d_in[3];
    const float* wq_conv = (const float*)d_in[4];
    const float* wk_conv = (const float*)d_in[5];
    const float* wv_conv = (const float*)d_in[6];
    const float* Wfa     = (const float*)d_in[7];
    const float* Wfb     = (const float*)d_in[8];
    const float* Wb      = (const float*)d_in[9];
    const float* Wga     = (const float*)d_in[10];
    const float* Wgb     = (const float*)d_in[11];
    const float* A_log   = (const float*)d_in[12];
    const float* dt_bias = (const float*)d_in[13];
    const float* o_norm_w= (const float*)d_in[14];
    const float* Wo      = (const float*)d_in[15];

    int BT = in_sizes[0] / HID;     // B*T
    int T = 1024;
    int B_ = BT / T;
    size_t M = (size_t)BT;
    size_t sz_big = M * HID;
    const int nW = HID * HID;       // 1M
    const int nS = D * HID;         // 131072
    const int NCAT = 3456;          // 3072 qkv | 256 fa/ga | 8 beta | 120 pad

    // ---- explicit workspace layout (no aliasing) ----
    float* fp = (float*)d_ws;
    float* QKVp = fp;               fp += 3 * sz_big;   // M x 3072 fused q|k|v
    float* Qc   = fp;               fp += sz_big;
    float* Kc   = fp;               fp += sz_big;
    float* Vc   = fp;               fp += sz_big;
    float* EGb  = fp;               fp += sz_big;
    float* GATE = fp;               fp += sz_big;
    float* Obuf = fp;               fp += sz_big;
    float* BETA = fp;               fp += M * H;
    bhalf* bp = (bhalf*)fp;
    bhalf* xb   = bp;               bp += sz_big;
    bhalf* Wcat = bp;               bp += (size_t)NCAT * HID;  // Wq|Wk|Wv|Wfa|Wga|Wb|pad
    bhalf* Wob  = bp;               bp += nW;
    bhalf* Wfbb = bp;               bp += nS;
    bhalf* Wgbb = bp;               bp += nS;
    bhalf* XAG  = bp;               bp += M * 256;          // M x 256: xa|xg
    bhalf* Obf  = bp;               bp += sz_big;

    dim3 blk(256);

    // casts (4 launches, vectorized x4)
    cast1<<<(int)((sz_big / 4 + 255) / 256), 256, 0, stream>>>(x, xb, (int)(sz_big / 4));
    cast4<<<dim3((nW / 4 + 255) / 256, 4), 256, 0, stream>>>(Wq, Wk, Wv, Wo,
        Wcat, Wcat + nW, Wcat + 2 * (size_t)nW, Wob, nW / 4);
    cast4<<<dim3((nS / 4 + 255) / 256, 4), 256, 0, stream>>>(Wfa, Wga, Wfb, Wgb,
        Wcat + 3 * (size_t)nW, Wcat + 3 * (size_t)nW + nS, Wfbb, Wgbb, nS / 4);
    cast1<<<(H * HID / 4 + 255) / 256, 256, 0, stream>>>(Wb,
        Wcat + 3 * (size_t)nW + 2 * (size_t)nS, H * HID / 4);

    // mega first-stage GEMM: [QKV | XA,XG | beta] = xb @ Wcat^T  (N=3456)
    gemm_bf16_nt<<<dim3(NCAT / 128, BT / 128), blk, 0, stream>>>(
        xb, Wcat, QKVp, BT, NCAT, HID, HID, HID, 3072, 3, nullptr, nullptr,
        nullptr, nullptr, nullptr, 0, XAG, BETA);

    // conv + silu (+norm) fused, one launch
    conv3_kernel<<<dim3(BT * H, 3), 128, 0, stream>>>(QKVp,
                                                      wq_conv, wk_conv, wv_conv,
                                                      Qc, Kc, Vc, T);

    // second stage batched (z=0: EGb w/ fused eg transform; z=1: GATE)
    gemm_bf16_nt<<<dim3(HID / 128, BT / 128, 2), blk, 0, stream>>>(
        XAG, Wfbb, EGb, BT, HID, D, 256, D, HID, 1, A_log, dt_bias,
        XAG + D, Wgbb, GATE, 0, nullptr, nullptr);

    // ---- chunked recurrence: QKVp (24MB) is dead after conv3; reuse it ----
    int nbh = B_ * 8;
    float* Uf   = QKVp;
    float* Aend = Uf + (size_t)nbh * 32 * 4096;
    hlf* Wn  = (hlf*)(Aend + (size_t)nbh * 32 * 128);
    hlf* Qt  = Wn  + (size_t)nbh * 32 * 4096;
    hlf* AoLp= Qt  + (size_t)nbh * 32 * 4096;
    hlf* KbT = AoLp + (size_t)nbh * 32 * 1024;

    chunk_prep_kernel<<<nbh * 32, 256, 0, stream>>>(Qc, Kc, Vc, EGb, BETA,
                                                    Wn, Uf, Qt, AoLp, KbT, Aend, T);
    chunk_scan_kernel<<<nbh * 4, 256, 0, stream>>>(Wn, Uf, Qt, AoLp, KbT, Aend,
                                                   Obuf, T);

    // output norm * gate -> bf16
    outnorm_kernel<<<BT * H, 128, 0, stream>>>(Obuf, GATE, o_norm_w, Obf, BT);

    // final projection (bf16 MFMA)
    gemm_bf16_nt<<<dim3(HID / 128, BT / 128), blk, 0, stream>>>(
        Obf, Wob, (float*)d_out, BT, HID, HID, HID, HID, HID, 0, nullptr, nullptr,
        nullptr, nullptr, nullptr, 0, nullptr, nullptr);
}

// Round 9
// 361.415 us; speedup vs baseline: 1.0236x; 1.0236x over previous
//
#include <hip/hip_runtime.h>
#include <hip/hip_bf16.h>
#include <math.h>

#define H 8
#define D 128
#define HID 1024
#define KCONV 4

typedef __bf16 bhalf;
typedef __bf16 bhalf4 __attribute__((ext_vector_type(4)));
typedef __bf16 bhalf8 __attribute__((ext_vector_type(8)));
typedef float f32x4 __attribute__((ext_vector_type(4)));
typedef _Float16 hlf;
typedef _Float16 half8 __attribute__((ext_vector_type(8)));
typedef _Float16 half4v __attribute__((ext_vector_type(4)));

// ---- async global->LDS (direct-to-shared DMA, bypasses VGPRs) ----
__device__ __forceinline__ void async16(const void* g, void* l) {
    __builtin_amdgcn_global_load_lds(
        (const __attribute__((address_space(1))) void*)g,
        (__attribute__((address_space(3))) void*)l, 16, 0, 0);
}

// ---------------- bf16 MFMA GEMM: C[M,N] = A[M,K]*B[N,K]^T ----------------
// 128x64 tile, BK=32, 256 threads (4 waves, 2x2), global_load_lds staging.
__global__ __launch_bounds__(256) void gemm_bf16_nt(const bhalf* A, const bhalf* B,
                                                    void* Cv,
                                                    int M, int N, int K,
                                                    int lda, int ldb, int ldc, int epi,
                                                    const float* __restrict__ A_log,
                                                    const float* __restrict__ dt_bias,
                                                    const bhalf* A2, const bhalf* B2,
                                                    void* C2, int epi2,
                                                    bhalf* __restrict__ pXAG,
                                                    float* __restrict__ pBETA)
{
    if (blockIdx.z) { A = A2; B = B2; Cv = C2; epi = epi2; }
    __shared__ __align__(16) bhalf As[128][32];   // 8 KB
    __shared__ __align__(16) bhalf Bs[64][32];    // 4 KB
    int tid = threadIdx.x;
    int wid = tid >> 6, lane = tid & 63;
    int rowBase = blockIdx.y * 128;
    int colBase = blockIdx.x * 64;
    int wm = wid >> 1, wn = wid & 1;

    f32x4 acc[4][2] = {};

    int r = lane >> 2;          // 16 rows per 1KB instr
    int cseg = lane & 3;        // 16B segment within 64B row

    for (int k0 = 0; k0 < K; k0 += 32) {
        __syncthreads();
#pragma unroll
        for (int s = 0; s < 3; ++s) {
            int j = wid * 3 + s;            // 12 instrs: 8 A + 4 B
            if (j < 8) {
                const bhalf* ga = A + (size_t)(rowBase + j * 16 + r) * lda + k0 + cseg * 8;
                async16(ga, &As[j * 16][0]);
            } else {
                int jb = j - 8;
                const bhalf* ga = B + (size_t)(colBase + jb * 16 + r) * ldb + k0 + cseg * 8;
                async16(ga, &Bs[jb * 16][0]);
            }
        }
        __syncthreads();
        int mq = lane & 15, kq = (lane >> 4) * 8;
        bhalf8 af[4], bfr[2];
#pragma unroll
        for (int mt = 0; mt < 4; ++mt)
            af[mt] = *(const bhalf8*)&As[wm * 64 + mt * 16 + mq][kq];
#pragma unroll
        for (int nt = 0; nt < 2; ++nt)
            bfr[nt] = *(const bhalf8*)&Bs[wn * 32 + nt * 16 + mq][kq];
#pragma unroll
        for (int mt = 0; mt < 4; ++mt)
#pragma unroll
            for (int nt = 0; nt < 2; ++nt)
                acc[mt][nt] = __builtin_amdgcn_mfma_f32_16x16x32_bf16(
                    af[mt], bfr[nt], acc[mt][nt], 0, 0, 0);
    }
    int rquad = (lane >> 4) * 4;
#pragma unroll
    for (int mt = 0; mt < 4; ++mt) {
        int m0 = rowBase + wm * 64 + mt * 16 + rquad;
#pragma unroll
        for (int nt = 0; nt < 2; ++nt) {
            int c = colBase + wn * 32 + (lane & 15) + nt * 16;
#pragma unroll
            for (int rr = 0; rr < 4; ++rr) {
                float val = acc[mt][nt][rr];
                int m = m0 + rr;
                if (epi == 0) {
                    ((float*)Cv)[(size_t)m * ldc + c] = val;
                } else if (epi == 1) {
                    int h = c >> 7, d = c & 127;
                    float z = val + dt_bias[h * D + d];
                    float sp = (z > 20.f) ? z : log1pf(expf(z));
                    ((float*)Cv)[(size_t)m * ldc + c] = expf(-expf(A_log[h]) * sp);
                } else if (epi == 2) {
                    ((bhalf*)Cv)[(size_t)m * ldc + c] = (bhalf)val;
                } else {
                    if (c < 3072) {
                        ((float*)Cv)[(size_t)m * 3072 + c] = val;
                    } else if (c < 3328) {
                        pXAG[(size_t)m * 256 + (c - 3072)] = (bhalf)val;
                    } else if (c < 3336) {
                        pBETA[(size_t)m * 8 + (c - 3328)] = 1.f / (1.f + expf(-val));
                    }
                }
            }
        }
    }
}

// ---------------- casts (vectorized, 4 elems/thread) ----------------
__global__ void cast1(const float* __restrict__ s, bhalf* __restrict__ d, int n4)
{
    int i = blockIdx.x * blockDim.x + threadIdx.x;
    if (i >= n4) return;
    float4 v = ((const float4*)s)[i];
    bhalf4 o = {(bhalf)v.x, (bhalf)v.y, (bhalf)v.z, (bhalf)v.w};
    ((bhalf4*)d)[i] = o;
}
__global__ void cast4(const float* __restrict__ s0, const float* __restrict__ s1,
                      const float* __restrict__ s2, const float* __restrict__ s3,
                      bhalf* __restrict__ d0, bhalf* __restrict__ d1,
                      bhalf* __restrict__ d2, bhalf* __restrict__ d3, int n4)
{
    int i = blockIdx.x * blockDim.x + threadIdx.x;
    if (i >= n4) return;
    int a = blockIdx.y;
    const float* s = (a == 0) ? s0 : (a == 1) ? s1 : (a == 2) ? s2 : s3;
    bhalf* d = (a == 0) ? d0 : (a == 1) ? d1 : (a == 2) ? d2 : d3;
    float4 v = ((const float4*)s)[i];
    bhalf4 o = {(bhalf)v.x, (bhalf)v.y, (bhalf)v.z, (bhalf)v.w};
    ((bhalf4*)d)[i] = o;
}

// ------- fused depthwise causal conv (K=4) + SiLU (+ rmsnorm*scale) --------
__global__ __launch_bounds__(128) void conv3_kernel(const float* __restrict__ QKV,
                                                    const float* __restrict__ wq,
                                                    const float* __restrict__ wk,
                                                    const float* __restrict__ wv,
                                                    float* __restrict__ Qc,
                                                    float* __restrict__ Kc,
                                                    float* __restrict__ Vc,
                                                    int T)
{
    int which = blockIdx.y;
    const float* w; float* out; int mode; float scale;
    if (which == 0)      { w = wq; out = Qc; mode = 1; scale = 1.0f / 128.0f; }
    else if (which == 1) { w = wk; out = Kc; mode = 1; scale = 0.08838834764831845f; }
    else                 { w = wv; out = Vc; mode = 0; scale = 1.f; }

    int bid = blockIdx.x;
    int h = bid % H;
    int t = (bid / H) % T;
    int b = bid / (H * T);
    int d = threadIdx.x;
    int c = h * D + d;
    const float* base = QKV + (size_t)b * T * 3072 + which * 1024 + c;
    float acc = 0.f;
#pragma unroll
    for (int j = 0; j < KCONV; ++j) {
        int tt = t - (KCONV - 1) + j;
        float xv = (tt >= 0) ? base[(size_t)tt * 3072] : 0.f;
        acc += xv * w[c * KCONV + j];
    }
    float y = acc / (1.f + expf(-acc));
    if (mode) {
        __shared__ float red[2];
        float ss = y * y;
#pragma unroll
        for (int s = 32; s > 0; s >>= 1) ss += __shfl_xor(ss, s, 64);
        if ((threadIdx.x & 63) == 0) red[threadIdx.x >> 6] = ss;
        __syncthreads();
        float tot = red[0] + red[1];
        float r = rsqrtf(tot * (1.f / D) + 1e-6f);
        y = y * r * scale;
    }
    out[(size_t)bid * D + d] = y;
}

// ---------------- DPP wave64 reduction ----------------
template <int CTRL>
__device__ __forceinline__ float dpp_add(float x) {
    int y = __builtin_amdgcn_update_dpp(0, __builtin_bit_cast(int, x),
                                        CTRL, 0xF, 0xF, false);
    return x + __builtin_bit_cast(float, y);
}
// after this chain the full-wave sum is valid in lane 63
__device__ __forceinline__ float wave_sum63(float x) {
    x = dpp_add<0x111>(x);   // row_shr:1
    x = dpp_add<0x112>(x);   // row_shr:2
    x = dpp_add<0x114>(x);   // row_shr:4
    x = dpp_add<0x118>(x);   // row_shr:8
    x = dpp_add<0x142>(x);   // row_bcast:15
    x = dpp_add<0x143>(x);   // row_bcast:31
    return x;
}

// =======================================================================
// Chunked gated-delta-rule (WY / UT-transform), chunk C = 32.
//   A_i[d]   = prod_{s<=i} e_s          suff_i[d]= prod_{s>i} e_s
//   R_ij[d]  = prod_{j<s<=i} e_s        (walked iteratively; all <=1)
//   P_ij  = sum_d k_i k_j R_ij  (i>j)   Ao_ij = sum_d q_i k_j R_ij (i>=j)
//   (I + diag(b) tril(P)) Delta = b*(V - Ktil S),  Ktil_i = k_i*A_i
//   O = Qtil S + tril(Ao) Delta;  S <- diag(A_end) S + Kbar^T Delta
// =======================================================================

// ---- pass 1: fully parallel per (bh, chunk). fp32 compute, f16 out. ----
// V staged through U_s; phase-3 reductions batched x4 (independent DPP
// chains pipeline; values bitwise identical).
__global__ __launch_bounds__(256) void chunk_prep_kernel(
    const float* __restrict__ Q, const float* __restrict__ K,
    const float* __restrict__ V, const float* __restrict__ E,
    const float* __restrict__ BETA,
    hlf* __restrict__ Wn, float* __restrict__ Uf, hlf* __restrict__ Qt,
    hlf* __restrict__ AoL, hlf* __restrict__ KbT, float* __restrict__ Aend,
    int T)
{
    __shared__ __align__(16) float e_s[32][128];   // 16K
    __shared__ __align__(16) float k_s[32][128];   // 16K
    __shared__ __align__(16) float U_s[32][128];   // 16K (V staged, then U)
    __shared__ __align__(16) hlf  A_s[32][128];    // 8K
    __shared__ __align__(16) hlf  W_s[32][128];    // 8K
    __shared__ float P_s[32][32];                  // 4K (beta-folded L)
    __shared__ float Ao_s[32][32];                 // 4K
    __shared__ float beta_s[32];

    int tid = threadIdx.x, wid = tid >> 6, lane = tid & 63;
    int bid = blockIdx.x;
    int bh = bid >> 5, ch = bid & 31;
    int b = bh >> 3, h = bh & 7;
    int t0 = ch * 32;
    size_t rowb = (size_t)(b * T + t0) * 1024 + h * 128;
    size_t co = (size_t)bh * 32 + ch;

    // ---- stage e,k,v (32 rows x 512B each; 1 async16 covers 2 rows) ----
    int rs2 = lane >> 5, seg = (lane & 31) * 4;
#pragma unroll
    for (int p = wid * 4; p < wid * 4 + 4; ++p) {
        int row = p * 2 + rs2;
        async16(E + rowb + (size_t)row * 1024 + seg, &e_s[p * 2][0]);
        async16(K + rowb + (size_t)row * 1024 + seg, &k_s[p * 2][0]);
        async16(V + rowb + (size_t)row * 1024 + seg, &U_s[p * 2][0]);
    }
    __syncthreads();

    // ---- phase 2: zero Ao, beta, cumulative products ----
    for (int x = tid; x < 1024; x += 256) Ao_s[x >> 5][x & 31] = 0.f;
    if (wid == 2 && lane < 32)
        beta_s[lane] = BETA[(size_t)(b * T + t0 + lane) * 8 + h];
    int d0 = lane * 2;
    if (wid == 0) {             // forward cumprod -> A_s, A_end
        float a0 = 1.f, a1 = 1.f;
        for (int t = 0; t < 32; ++t) {
            a0 *= e_s[t][d0]; a1 *= e_s[t][d0 + 1];
            A_s[t][d0] = (hlf)a0; A_s[t][d0 + 1] = (hlf)a1;
        }
        Aend[co * 128 + d0] = a0; Aend[co * 128 + d0 + 1] = a1;
    } else if (wid == 1) {      // backward suffix -> Kbar^T [d][t]
        float s0 = 1.f, s1 = 1.f;
        for (int t = 31; t >= 0; --t) {
            KbT[co * 4096 + (size_t)d0 * 32 + t]       = (hlf)(k_s[t][d0] * s0);
            KbT[co * 4096 + (size_t)(d0 + 1) * 32 + t] = (hlf)(k_s[t][d0 + 1] * s1);
            s0 *= e_s[t][d0]; s1 *= e_s[t][d0 + 1];
        }
    }
    __syncthreads();

    // ---- phase 3: P / Ao pairwise-decay triangle walk (j batched x4) ----
#pragma unroll
    for (int ii = 0; ii < 8; ++ii) {
        int i = wid + ii * 4;
        float ki0 = k_s[i][d0], ki1 = k_s[i][d0 + 1];
        float2 qv = *(const float2*)(Q + rowb + (size_t)i * 1024 + d0);
        float aa = wave_sum63(qv.x * ki0 + qv.y * ki1);
        if (lane == 63) Ao_s[i][i] = aa;           // diag: R = 1
        float R0 = 1.f, R1 = 1.f;
        int j = i - 1;
        for (; j >= 3; j -= 4) {
            float Ra0 = R0 * e_s[j + 1][d0],  Ra1 = R1 * e_s[j + 1][d0 + 1];
            float Rb0 = Ra0 * e_s[j][d0],     Rb1 = Ra1 * e_s[j][d0 + 1];
            float Rc0 = Rb0 * e_s[j - 1][d0], Rc1 = Rb1 * e_s[j - 1][d0 + 1];
            float Rd0 = Rc0 * e_s[j - 2][d0], Rd1 = Rc1 * e_s[j - 2][d0 + 1];
            float ua0 = Ra0 * k_s[j][d0],     ua1 = Ra1 * k_s[j][d0 + 1];
            float ub0 = Rb0 * k_s[j - 1][d0], ub1 = Rb1 * k_s[j - 1][d0 + 1];
            float uc0 = Rc0 * k_s[j - 2][d0], uc1 = Rc1 * k_s[j - 2][d0 + 1];
            float ud0 = Rd0 * k_s[j - 3][d0], ud1 = Rd1 * k_s[j - 3][d0 + 1];
            float p0 = wave_sum63(ki0 * ua0 + ki1 * ua1);
            float p1 = wave_sum63(ki0 * ub0 + ki1 * ub1);
            float p2 = wave_sum63(ki0 * uc0 + ki1 * uc1);
            float p3 = wave_sum63(ki0 * ud0 + ki1 * ud1);
            float a0 = wave_sum63(qv.x * ua0 + qv.y * ua1);
            float a1 = wave_sum63(qv.x * ub0 + qv.y * ub1);
            float a2 = wave_sum63(qv.x * uc0 + qv.y * uc1);
            float a3 = wave_sum63(qv.x * ud0 + qv.y * ud1);
            if (lane == 63) {
                P_s[i][j]     = p0; Ao_s[i][j]     = a0;
                P_s[i][j - 1] = p1; Ao_s[i][j - 1] = a1;
                P_s[i][j - 2] = p2; Ao_s[i][j - 2] = a2;
                P_s[i][j - 3] = p3; Ao_s[i][j - 3] = a3;
            }
            R0 = Rd0; R1 = Rd1;
        }
        for (; j >= 0; --j) {
            R0 *= e_s[j + 1][d0]; R1 *= e_s[j + 1][d0 + 1];
            float u0 = R0 * k_s[j][d0], u1 = R1 * k_s[j][d0 + 1];
            float pp = wave_sum63(ki0 * u0 + ki1 * u1);
            float a2 = wave_sum63(qv.x * u0 + qv.y * u1);
            if (lane == 63) { P_s[i][j] = pp; Ao_s[i][j] = a2; }
        }
    }
    __syncthreads();

    // ---- phase 4: fold beta into strict-lower L ----
    for (int x = tid; x < 1024; x += 256) {
        int i2 = x >> 5, j2 = x & 31;
        P_s[i2][j2] = (j2 < i2) ? P_s[i2][j2] * beta_s[i2] : 0.f;
    }
    __syncthreads();

    // ---- phase 5: (I+L)W = b*Ktil (wave0), (I+L)U = b*V (wave1), Qtil ----
    if (wid == 0) {
        for (int i = 0; i < 32; ++i) {
            float bb = beta_s[i];
            float a0 = bb * k_s[i][d0] * (float)A_s[i][d0];
            float a1 = bb * k_s[i][d0 + 1] * (float)A_s[i][d0 + 1];
            for (int k2 = 0; k2 < i; ++k2) {
                float L = P_s[i][k2];
                a0 -= L * (float)W_s[k2][d0];
                a1 -= L * (float)W_s[k2][d0 + 1];
            }
            W_s[i][d0] = (hlf)a0; W_s[i][d0 + 1] = (hlf)a1;
        }
    } else if (wid == 1) {
        for (int i = 0; i < 32; ++i) {
            float bb = beta_s[i];
            float2 vv = *(const float2*)&U_s[i][d0];   // staged V (LDS)
            float a0 = bb * vv.x, a1 = bb * vv.y;
            for (int k2 = 0; k2 < i; ++k2) {
                float L = P_s[i][k2];
                a0 -= L * U_s[k2][d0];
                a1 -= L * U_s[k2][d0 + 1];
            }
            U_s[i][d0] = a0; U_s[i][d0 + 1] = a1;      // overwrite V with U
        }
    } else {
        for (int r2 = wid - 2; r2 < 32; r2 += 2) {
            float2 qv = *(const float2*)(Q + rowb + (size_t)r2 * 1024 + d0);
            Qt[co * 4096 + (size_t)r2 * 128 + d0]     = (hlf)(qv.x * (float)A_s[r2][d0]);
            Qt[co * 4096 + (size_t)r2 * 128 + d0 + 1] = (hlf)(qv.y * (float)A_s[r2][d0 + 1]);
        }
    }
    __syncthreads();

    // ---- phase 6: dumps ----
    for (int x = tid; x < 4096; x += 256) {
        Wn[co * 4096 + x] = (hlf)(-(float)W_s[x >> 7][x & 127]);
        Uf[co * 4096 + x] = U_s[x >> 7][x & 127];
    }
    for (int x = tid; x < 1024; x += 256)
        AoL[co * 1024 + x] = (hlf)Ao_s[x >> 5][x & 31];
}

// ---- pass 2: serial chunk scan. S in registers; global loads are volatile
// asm, DEPTH-2 rotation with uniform robust wait vmcnt(21). Qtil@S MFMAs
// hoisted before barrier1 (no Dt dependency) to hide the Dt ds_write.
struct ScanOps {
    half8 aw0, aw1, aw2, aw3;
    half8 aq0, aq1, aq2, aq3;
    half8 bK0, bK1, bK2, bK3;
    half8 aA;
    float u0, u1, u2, u3;
    f32x4 ae0, ae1, ae2, ae3;
};

#define GLOAD16(dst, ptr) \
    asm volatile("global_load_dwordx4 %0, %1, off" : "=v"(dst) : "v"(ptr))
#define GLOAD4(dst, ptr) \
    asm volatile("global_load_dword %0, %1, off" : "=v"(dst) : "v"(ptr))

#define SCAN_WAIT21(o) \
    asm volatile("s_waitcnt vmcnt(21)" \
        : "+v"(o.aw0), "+v"(o.aw1), "+v"(o.aw2), "+v"(o.aw3), \
          "+v"(o.aq0), "+v"(o.aq1), "+v"(o.aq2), "+v"(o.aq3), \
          "+v"(o.aA), \
          "+v"(o.bK0), "+v"(o.bK1), "+v"(o.bK2), "+v"(o.bK3), \
          "+v"(o.u0), "+v"(o.u1), "+v"(o.u2), "+v"(o.u3), \
          "+v"(o.ae0), "+v"(o.ae1), "+v"(o.ae2), "+v"(o.ae3))

__device__ __forceinline__ void scan_load(ScanOps& o, size_t co,
    const hlf* __restrict__ Wn, const float* __restrict__ Uf,
    const hlf* __restrict__ Qt, const hlf* __restrict__ Ao,
    const hlf* __restrict__ KbT, const float* __restrict__ Aend,
    int tr, int vc, int dseg, int mq, int kq, int rq, int v0)
{
    const hlf*   Wc  = Wn  + co * 4096;
    const hlf*   Qc  = Qt  + co * 4096;
    const hlf*   Aoc = Ao  + co * 1024;
    const hlf*   Kbc = KbT + co * 4096;
    const float* Uc  = Uf  + co * 4096;
    const float* Aec = Aend + co * 128;
    size_t rw = (size_t)(tr + mq) * 128 + kq;
    GLOAD16(o.aw0, &Wc[rw]);
    GLOAD16(o.aw1, &Wc[rw + 32]);
    GLOAD16(o.aw2, &Wc[rw + 64]);
    GLOAD16(o.aw3, &Wc[rw + 96]);
    GLOAD16(o.aq0, &Qc[rw]);
    GLOAD16(o.aq1, &Qc[rw + 32]);
    GLOAD16(o.aq2, &Qc[rw + 64]);
    GLOAD16(o.aq3, &Qc[rw + 96]);
    GLOAD16(o.aA,  &Aoc[(tr + mq) * 32 + kq]);
    GLOAD16(o.bK0, &Kbc[(size_t)(dseg + mq) * 32 + kq]);
    GLOAD16(o.bK1, &Kbc[(size_t)(dseg + 16 + mq) * 32 + kq]);
    GLOAD16(o.bK2, &Kbc[(size_t)(dseg + 32 + mq) * 32 + kq]);
    GLOAD16(o.bK3, &Kbc[(size_t)(dseg + 48 + mq) * 32 + kq]);
    size_t ru = (size_t)(tr + rq) * 128 + v0 + vc + mq;
    GLOAD4(o.u0, &Uc[ru]);
    GLOAD4(o.u1, &Uc[ru + 128]);
    GLOAD4(o.u2, &Uc[ru + 256]);
    GLOAD4(o.u3, &Uc[ru + 384]);
    GLOAD16(o.ae0, &Aec[dseg + rq]);
    GLOAD16(o.ae1, &Aec[dseg + 16 + rq]);
    GLOAD16(o.ae2, &Aec[dseg + 32 + rq]);
    GLOAD16(o.ae3, &Aec[dseg + 48 + rq]);
}

__device__ __forceinline__ void scan_body(const ScanOps& o, int c,
    f32x4* sreg, hlf (*Sh)[136], hlf (*Dt)[40], float* __restrict__ O,
    int b, int h, int v0s, int T, int Mrows,
    int tr, int vc, int vtile, int dseg, int mq, int kq, int rq)
{
    // Sh reads (shared between Delta and O phases; held in regs across bar1)
    half8 bs0 = *(const half8*)&Sh[vc + mq][kq];
    half8 bs1 = *(const half8*)&Sh[vc + mq][32 + kq];
    half8 bs2 = *(const half8*)&Sh[vc + mq][64 + kq];
    half8 bs3 = *(const half8*)&Sh[vc + mq][96 + kq];

    // ---- Delta = U + (-W) @ S ----
    f32x4 dacc = {o.u0, o.u1, o.u2, o.u3};
    dacc = __builtin_amdgcn_mfma_f32_16x16x32_f16(o.aw0, bs0, dacc, 0, 0, 0);
    dacc = __builtin_amdgcn_mfma_f32_16x16x32_f16(o.aw1, bs1, dacc, 0, 0, 0);
    dacc = __builtin_amdgcn_mfma_f32_16x16x32_f16(o.aw2, bs2, dacc, 0, 0, 0);
    dacc = __builtin_amdgcn_mfma_f32_16x16x32_f16(o.aw3, bs3, dacc, 0, 0, 0);
    half4v dh4 = {(hlf)dacc[0], (hlf)dacc[1], (hlf)dacc[2], (hlf)dacc[3]};
    *(half4v*)&Dt[vc + mq][tr + rq] = dh4;

    // ---- O partial: Qtil @ S (no Dt dependency -> hides Dt ds_write) ----
    f32x4 oacc = {0.f, 0.f, 0.f, 0.f};
    oacc = __builtin_amdgcn_mfma_f32_16x16x32_f16(o.aq0, bs0, oacc, 0, 0, 0);
    oacc = __builtin_amdgcn_mfma_f32_16x16x32_f16(o.aq1, bs1, oacc, 0, 0, 0);
    oacc = __builtin_amdgcn_mfma_f32_16x16x32_f16(o.aq2, bs2, oacc, 0, 0, 0);
    oacc = __builtin_amdgcn_mfma_f32_16x16x32_f16(o.aq3, bs3, oacc, 0, 0, 0);

    asm volatile("s_waitcnt lgkmcnt(0)" ::: "memory");
    __builtin_amdgcn_s_barrier();
    __builtin_amdgcn_sched_barrier(0);

    // ---- O += Ao @ Delta ----
    half8 bD = *(const half8*)&Dt[vc + mq][kq];
    oacc = __builtin_amdgcn_mfma_f32_16x16x32_f16(o.aA, bD, oacc, 0, 0, 0);
    // O split per v-slice: O4[vs][bt][h][32] -- no cross-XCD line sharing
    size_t ob = (size_t)v0s * Mrows * 256 +
                ((size_t)(b * T + c * 32 + tr + rq) * 8 + h) * 32 + vc + mq;
    O[ob]       = oacc[0];
    O[ob + 256] = oacc[1];
    O[ob + 512] = oacc[2];
    O[ob + 768] = oacc[3];

    // ---- S' = diag(Aend)*S + Kbar^T @ Delta, C[m=d][n=v] (register state) ----
    half8 aD = *(const half8*)&Dt[vtile + mq][kq];
    f32x4 s0 = sreg[0] * o.ae0;
    f32x4 s1 = sreg[1] * o.ae1;
    f32x4 s2 = sreg[2] * o.ae2;
    f32x4 s3 = sreg[3] * o.ae3;
    s0 = __builtin_amdgcn_mfma_f32_16x16x32_f16(o.bK0, aD, s0, 0, 0, 0);
    s1 = __builtin_amdgcn_mfma_f32_16x16x32_f16(o.bK1, aD, s1, 0, 0, 0);
    s2 = __builtin_amdgcn_mfma_f32_16x16x32_f16(o.bK2, aD, s2, 0, 0, 0);
    s3 = __builtin_amdgcn_mfma_f32_16x16x32_f16(o.bK3, aD, s3, 0, 0, 0);
    sreg[0] = s0; sreg[1] = s1; sreg[2] = s2; sreg[3] = s3;
    {   // f16 operand copy, vector half4 writes (4 consecutive d at fixed v)
        half4v h0 = {(hlf)s0[0], (hlf)s0[1], (hlf)s0[2], (hlf)s0[3]};
        half4v h1 = {(hlf)s1[0], (hlf)s1[1], (hlf)s1[2], (hlf)s1[3]};
        half4v h2 = {(hlf)s2[0], (hlf)s2[1], (hlf)s2[2], (hlf)s2[3]};
        half4v h3 = {(hlf)s3[0], (hlf)s3[1], (hlf)s3[2], (hlf)s3[3]};
        *(half4v*)&Sh[vtile + mq][dseg + rq]      = h0;
        *(half4v*)&Sh[vtile + mq][dseg + 16 + rq] = h1;
        *(half4v*)&Sh[vtile + mq][dseg + 32 + rq] = h2;
        *(half4v*)&Sh[vtile + mq][dseg + 48 + rq] = h3;
    }
    asm volatile("s_waitcnt lgkmcnt(0)" ::: "memory");
    __builtin_amdgcn_s_barrier();
    __builtin_amdgcn_sched_barrier(0);
}

// grid = nbh*4 (bh-major: the 4 v-splits of one bh land on the same XCD).
__global__ __launch_bounds__(256, 1) void chunk_scan_kernel(
    const hlf* __restrict__ Wn, const float* __restrict__ Uf,
    const hlf* __restrict__ Qt, const hlf* __restrict__ Ao,
    const hlf* __restrict__ KbT, const float* __restrict__ Aend,
    float* __restrict__ O, int T)
{
    __shared__ __align__(16) hlf  Sh[32][136];   // f16 S copy for MFMA B-reads
    __shared__ __align__(16) hlf  Dt[32][40];    // Delta^T [v][t] f16

    int tid = threadIdx.x, wid = tid >> 6, lane = tid & 63;
    int nbh = gridDim.x >> 2;
    int bh = blockIdx.x % nbh, vs = blockIdx.x / nbh;
    int b = bh >> 3, h = bh & 7;
    int v0 = vs * 32;
    int Mrows = (nbh >> 3) * T;

    for (int x = tid; x < 32 * 136; x += 256) ((hlf*)Sh)[x] = (hlf)0.f;

    int mq = lane & 15, kq = (lane >> 4) * 8, rq = (lane >> 4) * 4;
    int tr = (wid >> 1) * 16, vc = (wid & 1) * 16;      // Delta/O tile
    int vtile = (wid >> 1) * 16, dseg = (wid & 1) * 64; // S-update tiles

    f32x4 sreg[4] = {};   // S[d][v] register master (C[m=d][n=v] fragments)

    int NC = T / 32;
    size_t cb = (size_t)bh * 32;
    size_t comax = (size_t)nbh * 32 - 1;   // clamp for tail prefetches

    // barrier WITHOUT vmcnt drain (raw s_barrier; Sh init is DS -> lgkm only)
    asm volatile("s_waitcnt lgkmcnt(0)" ::: "memory");
    __builtin_amdgcn_s_barrier();

    ScanOps op0, op1;
    scan_load(op0, cb,     Wn, Uf, Qt, Ao, KbT, Aend, tr, vc, dseg, mq, kq, rq, v0);
    scan_load(op1, cb + 1, Wn, Uf, Qt, Ao, KbT, Aend, tr, vc, dseg, mq, kq, rq, v0);

#define CCLAMP(x) ((x) > comax ? comax : (x))
    for (int cc = 0; cc < NC; cc += 2) {
        SCAN_WAIT21(op0);
        scan_body(op0, cc, sreg, Sh, Dt, O, b, h, vs, T, Mrows,
                  tr, vc, vtile, dseg, mq, kq, rq);
        scan_load(op0, CCLAMP(cb + cc + 2), Wn, Uf, Qt, Ao, KbT, Aend,
                  tr, vc, dseg, mq, kq, rq, v0);

        SCAN_WAIT21(op1);
        scan_body(op1, cc + 1, sreg, Sh, Dt, O, b, h, vs, T, Mrows,
                  tr, vc, vtile, dseg, mq, kq, rq);
        scan_load(op1, CCLAMP(cb + cc + 3), Wn, Uf, Qt, Ao, KbT, Aend,
                  tr, vc, dseg, mq, kq, rq, v0);
    }
#undef CCLAMP
}

// -------- out = rmsnorm(o)*w*sigmoid(gate) -> bf16 (for final MFMA GEMM) ----
// O is the 4-way v-split layout: O4[vs][bt][h][32]
__global__ __launch_bounds__(128) void outnorm_kernel(const float* __restrict__ O,
                                                      const float* __restrict__ GATE,
                                                      const float* __restrict__ w,
                                                      bhalf* __restrict__ Obf,
                                                      int Mrows)
{
    int bid = blockIdx.x;
    int d = threadIdx.x;
    size_t base = (size_t)bid * D;
    float y = O[(size_t)(d >> 5) * Mrows * 256 + (size_t)bid * 32 + (d & 31)];
    __shared__ float red[2];
    float ss = y * y;
#pragma unroll
    for (int s = 32; s > 0; s >>= 1) ss += __shfl_xor(ss, s, 64);
    if ((threadIdx.x & 63) == 0) red[threadIdx.x >> 6] = ss;
    __syncthreads();
    float tot = red[0] + red[1];
    float r = rsqrtf(tot * (1.f / D) + 1e-5f);
    float gz = GATE[base + d];
    float sg = 1.f / (1.f + expf(-gz));
    Obf[base + d] = (bhalf)(y * r * w[d] * sg);
}

extern "C" void kernel_launch(void* const* d_in, const int* in_sizes, int n_in,
                              void* d_out, int out_size, void* d_ws, size_t ws_size,
                              hipStream_t stream)
{
    const float* x       = (const float*)d_in[0];
    const float* Wq      = (const float*)d_in[1];
    const float* Wk      = (const float*)d_in[2];
    const float* Wv      = (const float*)d_in[3];
    const float* wq_conv = (const float*)d_in[4];
    const float* wk_conv = (const float*)d_in[5];
    const float* wv_conv = (const float*)d_in[6];
    const float* Wfa     = (const float*)d_in[7];
    const float* Wfb     = (const float*)d_in[8];
    const float* Wb      = (const float*)d_in[9];
    const float* Wga     = (const float*)d_in[10];
    const float* Wgb     = (const float*)d_in[11];
    const float* A_log   = (const float*)d_in[12];
    const float* dt_bias = (const float*)d_in[13];
    const float* o_norm_w= (const float*)d_in[14];
    const float* Wo      = (const float*)d_in[15];

    int BT = in_sizes[0] / HID;     // B*T
    int T = 1024;
    int B_ = BT / T;
    size_t M = (size_t)BT;
    size_t sz_big = M * HID;
    const int nW = HID * HID;       // 1M
    const int nS = D * HID;         // 131072
    const int NCAT = 3392;          // 3072 qkv | 256 fa/ga | 8 beta | 56 pad

    // ---- explicit workspace layout (no aliasing) ----
    float* fp = (float*)d_ws;
    float* QKVp = fp;               fp += 3 * sz_big;   // M x 3072 fused q|k|v
    float* Qc   = fp;               fp += sz_big;
    float* Kc   = fp;               fp += sz_big;
    float* Vc   = fp;               fp += sz_big;
    float* EGb  = fp;               fp += sz_big;
    float* GATE = fp;               fp += sz_big;
    float* Obuf = fp;               fp += sz_big;
    float* BETA = fp;               fp += M * H;
    bhalf* bp = (bhalf*)fp;
    bhalf* xb   = bp;               bp += sz_big;
    bhalf* Wcat = bp;               bp += (size_t)NCAT * HID;  // Wq|Wk|Wv|Wfa|Wga|Wb|pad
    bhalf* Wob  = bp;               bp += nW;
    bhalf* Wfbb = bp;               bp += nS;
    bhalf* Wgbb = bp;               bp += nS;
    bhalf* XAG  = bp;               bp += M * 256;          // M x 256: xa|xg
    bhalf* Obf  = bp;               bp += sz_big;

    dim3 blk(256);

    // casts (4 launches, vectorized x4)
    cast1<<<(int)((sz_big / 4 + 255) / 256), 256, 0, stream>>>(x, xb, (int)(sz_big / 4));
    cast4<<<dim3((nW / 4 + 255) / 256, 4), 256, 0, stream>>>(Wq, Wk, Wv, Wo,
        Wcat, Wcat + nW, Wcat + 2 * (size_t)nW, Wob, nW / 4);
    cast4<<<dim3((nS / 4 + 255) / 256, 4), 256, 0, stream>>>(Wfa, Wga, Wfb, Wgb,
        Wcat + 3 * (size_t)nW, Wcat + 3 * (size_t)nW + nS, Wfbb, Wgbb, nS / 4);
    cast1<<<(H * HID / 4 + 255) / 256, 256, 0, stream>>>(Wb,
        Wcat + 3 * (size_t)nW + 2 * (size_t)nS, H * HID / 4);

    // mega first-stage GEMM: [QKV | XA,XG | beta] = xb @ Wcat^T  (N=3392)
    gemm_bf16_nt<<<dim3(NCAT / 64, BT / 128), blk, 0, stream>>>(
        xb, Wcat, QKVp, BT, NCAT, HID, HID, HID, 3072, 3, nullptr, nullptr,
        nullptr, nullptr, nullptr, 0, XAG, BETA);

    // conv + silu (+norm) fused, one launch
    conv3_kernel<<<dim3(BT * H, 3), 128, 0, stream>>>(QKVp,
                                                      wq_conv, wk_conv, wv_conv,
                                                      Qc, Kc, Vc, T);

    // second stage batched (z=0: EGb w/ fused eg transform; z=1: GATE)
    gemm_bf16_nt<<<dim3(HID / 64, BT / 128, 2), blk, 0, stream>>>(
        XAG, Wfbb, EGb, BT, HID, D, 256, D, HID, 1, A_log, dt_bias,
        XAG + D, Wgbb, GATE, 0, nullptr, nullptr);

    // ---- chunked recurrence: QKVp (24MB) is dead after conv3; reuse it ----
    int nbh = B_ * 8;
    float* Uf   = QKVp;
    float* Aend = Uf + (size_t)nbh * 32 * 4096;
    hlf* Wn  = (hlf*)(Aend + (size_t)nbh * 32 * 128);
    hlf* Qt  = Wn  + (size_t)nbh * 32 * 4096;
    hlf* AoLp= Qt  + (size_t)nbh * 32 * 4096;
    hlf* KbT = AoLp + (size_t)nbh * 32 * 1024;

    chunk_prep_kernel<<<nbh * 32, 256, 0, stream>>>(Qc, Kc, Vc, EGb, BETA,
                                                    Wn, Uf, Qt, AoLp, KbT, Aend, T);
    chunk_scan_kernel<<<nbh * 4, 256, 0, stream>>>(Wn, Uf, Qt, AoLp, KbT, Aend,
                                                   Obuf, T);

    // output norm * gate -> bf16
    outnorm_kernel<<<BT * H, 128, 0, stream>>>(Obuf, GATE, o_norm_w, Obf, BT);

    // final projection (bf16 MFMA)
    gemm_bf16_nt<<<dim3(HID / 64, BT / 128), blk, 0, stream>>>(
        Obf, Wob, (float*)d_out, BT, HID, HID, HID, HID, HID, 0, nullptr, nullptr,
        nullptr, nullptr, nullptr, 0, nullptr, nullptr);
}

// Round 10
// 309.287 us; speedup vs baseline: 1.1961x; 1.1685x over previous
//
#include <hip/hip_runtime.h>
#include <hip/hip_bf16.h>
#include <math.h>

#define H 8
#define D 128
#define HID 1024
#define KCONV 4

typedef __bf16 bhalf;
typedef __bf16 bhalf4 __attribute__((ext_vector_type(4)));
typedef __bf16 bhalf8 __attribute__((ext_vector_type(8)));
typedef float f32x4 __attribute__((ext_vector_type(4)));
typedef _Float16 hlf;
typedef _Float16 half8 __attribute__((ext_vector_type(8)));
typedef _Float16 half4v __attribute__((ext_vector_type(4)));

// ---- async global->LDS (direct-to-shared DMA, bypasses VGPRs) ----
__device__ __forceinline__ void async16(const void* g, void* l) {
    __builtin_amdgcn_global_load_lds(
        (const __attribute__((address_space(1))) void*)g,
        (__attribute__((address_space(3))) void*)l, 16, 0, 0);
}

// ---------------- bf16 MFMA GEMM: C[M,N] = A[M,K]*B[N,K]^T ----------------
// 128x64 tile, BK=32, 256 threads (4 waves, 2x2), global_load_lds staging.
__global__ __launch_bounds__(256) void gemm_bf16_nt(const bhalf* A, const bhalf* B,
                                                    void* Cv,
                                                    int M, int N, int K,
                                                    int lda, int ldb, int ldc, int epi,
                                                    const float* __restrict__ A_log,
                                                    const float* __restrict__ dt_bias,
                                                    const bhalf* A2, const bhalf* B2,
                                                    void* C2, int epi2,
                                                    bhalf* __restrict__ pXAG,
                                                    float* __restrict__ pBETA)
{
    if (blockIdx.z) { A = A2; B = B2; Cv = C2; epi = epi2; }
    __shared__ __align__(16) bhalf As[128][32];   // 8 KB
    __shared__ __align__(16) bhalf Bs[64][32];    // 4 KB
    int tid = threadIdx.x;
    int wid = tid >> 6, lane = tid & 63;
    int rowBase = blockIdx.y * 128;
    int colBase = blockIdx.x * 64;
    int wm = wid >> 1, wn = wid & 1;

    f32x4 acc[4][2] = {};

    int r = lane >> 2;          // 16 rows per 1KB instr
    int cseg = lane & 3;        // 16B segment within 64B row

    for (int k0 = 0; k0 < K; k0 += 32) {
        __syncthreads();
#pragma unroll
        for (int s = 0; s < 3; ++s) {
            int j = wid * 3 + s;            // 12 instrs: 8 A + 4 B
            if (j < 8) {
                const bhalf* ga = A + (size_t)(rowBase + j * 16 + r) * lda + k0 + cseg * 8;
                async16(ga, &As[j * 16][0]);
            } else {
                int jb = j - 8;
                const bhalf* ga = B + (size_t)(colBase + jb * 16 + r) * ldb + k0 + cseg * 8;
                async16(ga, &Bs[jb * 16][0]);
            }
        }
        __syncthreads();
        int mq = lane & 15, kq = (lane >> 4) * 8;
        bhalf8 af[4], bfr[2];
#pragma unroll
        for (int mt = 0; mt < 4; ++mt)
            af[mt] = *(const bhalf8*)&As[wm * 64 + mt * 16 + mq][kq];
#pragma unroll
        for (int nt = 0; nt < 2; ++nt)
            bfr[nt] = *(const bhalf8*)&Bs[wn * 32 + nt * 16 + mq][kq];
#pragma unroll
        for (int mt = 0; mt < 4; ++mt)
#pragma unroll
            for (int nt = 0; nt < 2; ++nt)
                acc[mt][nt] = __builtin_amdgcn_mfma_f32_16x16x32_bf16(
                    af[mt], bfr[nt], acc[mt][nt], 0, 0, 0);
    }
    int rquad = (lane >> 4) * 4;
#pragma unroll
    for (int mt = 0; mt < 4; ++mt) {
        int m0 = rowBase + wm * 64 + mt * 16 + rquad;
#pragma unroll
        for (int nt = 0; nt < 2; ++nt) {
            int c = colBase + wn * 32 + (lane & 15) + nt * 16;
#pragma unroll
            for (int rr = 0; rr < 4; ++rr) {
                float val = acc[mt][nt][rr];
                int m = m0 + rr;
                if (epi == 0) {
                    ((float*)Cv)[(size_t)m * ldc + c] = val;
                } else if (epi == 1) {
                    int h = c >> 7, d = c & 127;
                    float z = val + dt_bias[h * D + d];
                    float sp = (z > 20.f) ? z : log1pf(expf(z));
                    ((float*)Cv)[(size_t)m * ldc + c] = expf(-expf(A_log[h]) * sp);
                } else if (epi == 2) {
                    ((bhalf*)Cv)[(size_t)m * ldc + c] = (bhalf)val;
                } else {
                    if (c < 3072) {
                        ((float*)Cv)[(size_t)m * 3072 + c] = val;
                    } else if (c < 3328) {
                        pXAG[(size_t)m * 256 + (c - 3072)] = (bhalf)val;
                    } else if (c < 3336) {
                        pBETA[(size_t)m * 8 + (c - 3328)] = 1.f / (1.f + expf(-val));
                    }
                }
            }
        }
    }
}

// ---------------- casts (vectorized, 4 elems/thread) ----------------
__global__ void cast1(const float* __restrict__ s, bhalf* __restrict__ d, int n4)
{
    int i = blockIdx.x * blockDim.x + threadIdx.x;
    if (i >= n4) return;
    float4 v = ((const float4*)s)[i];
    bhalf4 o = {(bhalf)v.x, (bhalf)v.y, (bhalf)v.z, (bhalf)v.w};
    ((bhalf4*)d)[i] = o;
}
__global__ void cast4(const float* __restrict__ s0, const float* __restrict__ s1,
                      const float* __restrict__ s2, const float* __restrict__ s3,
                      bhalf* __restrict__ d0, bhalf* __restrict__ d1,
                      bhalf* __restrict__ d2, bhalf* __restrict__ d3, int n4)
{
    int i = blockIdx.x * blockDim.x + threadIdx.x;
    if (i >= n4) return;
    int a = blockIdx.y;
    const float* s = (a == 0) ? s0 : (a == 1) ? s1 : (a == 2) ? s2 : s3;
    bhalf* d = (a == 0) ? d0 : (a == 1) ? d1 : (a == 2) ? d2 : d3;
    float4 v = ((const float4*)s)[i];
    bhalf4 o = {(bhalf)v.x, (bhalf)v.y, (bhalf)v.z, (bhalf)v.w};
    ((bhalf4*)d)[i] = o;
}

// ------- fused depthwise causal conv (K=4) + SiLU (+ rmsnorm*scale) --------
__global__ __launch_bounds__(128) void conv3_kernel(const float* __restrict__ QKV,
                                                    const float* __restrict__ wq,
                                                    const float* __restrict__ wk,
                                                    const float* __restrict__ wv,
                                                    float* __restrict__ Qc,
                                                    float* __restrict__ Kc,
                                                    float* __restrict__ Vc,
                                                    int T)
{
    int which = blockIdx.y;
    const float* w; float* out; int mode; float scale;
    if (which == 0)      { w = wq; out = Qc; mode = 1; scale = 1.0f / 128.0f; }
    else if (which == 1) { w = wk; out = Kc; mode = 1; scale = 0.08838834764831845f; }
    else                 { w = wv; out = Vc; mode = 0; scale = 1.f; }

    int bid = blockIdx.x;
    int h = bid % H;
    int t = (bid / H) % T;
    int b = bid / (H * T);
    int d = threadIdx.x;
    int c = h * D + d;
    const float* base = QKV + (size_t)b * T * 3072 + which * 1024 + c;
    float acc = 0.f;
#pragma unroll
    for (int j = 0; j < KCONV; ++j) {
        int tt = t - (KCONV - 1) + j;
        float xv = (tt >= 0) ? base[(size_t)tt * 3072] : 0.f;
        acc += xv * w[c * KCONV + j];
    }
    float y = acc / (1.f + expf(-acc));
    if (mode) {
        __shared__ float red[2];
        float ss = y * y;
#pragma unroll
        for (int s = 32; s > 0; s >>= 1) ss += __shfl_xor(ss, s, 64);
        if ((threadIdx.x & 63) == 0) red[threadIdx.x >> 6] = ss;
        __syncthreads();
        float tot = red[0] + red[1];
        float r = rsqrtf(tot * (1.f / D) + 1e-6f);
        y = y * r * scale;
    }
    out[(size_t)bid * D + d] = y;
}

// ---------------- DPP wave64 reduction ----------------
template <int CTRL>
__device__ __forceinline__ float dpp_add(float x) {
    int y = __builtin_amdgcn_update_dpp(0, __builtin_bit_cast(int, x),
                                        CTRL, 0xF, 0xF, false);
    return x + __builtin_bit_cast(float, y);
}
// after this chain the full-wave sum is valid in lane 63
__device__ __forceinline__ float wave_sum63(float x) {
    x = dpp_add<0x111>(x);   // row_shr:1
    x = dpp_add<0x112>(x);   // row_shr:2
    x = dpp_add<0x114>(x);   // row_shr:4
    x = dpp_add<0x118>(x);   // row_shr:8
    x = dpp_add<0x142>(x);   // row_bcast:15
    x = dpp_add<0x143>(x);   // row_bcast:31
    return x;
}

// =======================================================================
// Chunked gated-delta-rule (WY / UT-transform), chunk C = 32.
//   A_i[d]   = prod_{s<=i} e_s          suff_i[d]= prod_{s>i} e_s
//   R_ij[d]  = prod_{j<s<=i} e_s        (walked iteratively; all <=1)
//   P_ij  = sum_d k_i k_j R_ij  (i>j)   Ao_ij = sum_d q_i k_j R_ij (i>=j)
//   (I + diag(b) tril(P)) Delta = b*(V - Ktil S),  Ktil_i = k_i*A_i
//   O = Qtil S + tril(Ao) Delta;  S <- diag(A_end) S + Kbar^T Delta
// =======================================================================

// ---- pass 1: fully parallel per (bh, chunk). fp32 compute, f16 out. ----
// V staged through U_s (in-place read->overwrite) so phase 5's serial
// substitution chain never waits on HBM. LDS 72K -> 2 blocks/CU.
__global__ __launch_bounds__(256) void chunk_prep_kernel(
    const float* __restrict__ Q, const float* __restrict__ K,
    const float* __restrict__ V, const float* __restrict__ E,
    const float* __restrict__ BETA,
    hlf* __restrict__ Wn, float* __restrict__ Uf, hlf* __restrict__ Qt,
    hlf* __restrict__ AoL, hlf* __restrict__ KbT, float* __restrict__ Aend,
    int T)
{
    __shared__ __align__(16) float e_s[32][128];   // 16K
    __shared__ __align__(16) float k_s[32][128];   // 16K
    __shared__ __align__(16) float U_s[32][128];   // 16K (V staged, then U)
    __shared__ __align__(16) hlf  A_s[32][128];    // 8K
    __shared__ __align__(16) hlf  W_s[32][128];    // 8K
    __shared__ float P_s[32][32];                  // 4K (beta-folded L)
    __shared__ float Ao_s[32][32];                 // 4K
    __shared__ float beta_s[32];

    int tid = threadIdx.x, wid = tid >> 6, lane = tid & 63;
    int bid = blockIdx.x;
    int bh = bid >> 5, ch = bid & 31;
    int b = bh >> 3, h = bh & 7;
    int t0 = ch * 32;
    size_t rowb = (size_t)(b * T + t0) * 1024 + h * 128;
    size_t co = (size_t)bh * 32 + ch;

    // ---- stage e,k,v (32 rows x 512B each; 1 async16 covers 2 rows) ----
    int rs2 = lane >> 5, seg = (lane & 31) * 4;
#pragma unroll
    for (int p = wid * 4; p < wid * 4 + 4; ++p) {
        int row = p * 2 + rs2;
        async16(E + rowb + (size_t)row * 1024 + seg, &e_s[p * 2][0]);
        async16(K + rowb + (size_t)row * 1024 + seg, &k_s[p * 2][0]);
        async16(V + rowb + (size_t)row * 1024 + seg, &U_s[p * 2][0]);
    }
    __syncthreads();

    // ---- phase 2: zero Ao, beta, cumulative products ----
    for (int x = tid; x < 1024; x += 256) Ao_s[x >> 5][x & 31] = 0.f;
    if (wid == 2 && lane < 32)
        beta_s[lane] = BETA[(size_t)(b * T + t0 + lane) * 8 + h];
    int d0 = lane * 2;
    if (wid == 0) {             // forward cumprod -> A_s, A_end
        float a0 = 1.f, a1 = 1.f;
        for (int t = 0; t < 32; ++t) {
            a0 *= e_s[t][d0]; a1 *= e_s[t][d0 + 1];
            A_s[t][d0] = (hlf)a0; A_s[t][d0 + 1] = (hlf)a1;
        }
        Aend[co * 128 + d0] = a0; Aend[co * 128 + d0 + 1] = a1;
    } else if (wid == 1) {      // backward suffix -> Kbar^T [d][t]
        float s0 = 1.f, s1 = 1.f;
        for (int t = 31; t >= 0; --t) {
            KbT[co * 4096 + (size_t)d0 * 32 + t]       = (hlf)(k_s[t][d0] * s0);
            KbT[co * 4096 + (size_t)(d0 + 1) * 32 + t] = (hlf)(k_s[t][d0 + 1] * s1);
            s0 *= e_s[t][d0]; s1 *= e_s[t][d0 + 1];
        }
    }
    __syncthreads();

    // ---- phase 3: P / Ao pairwise-decay triangle walk ----
#pragma unroll
    for (int ii = 0; ii < 8; ++ii) {
        int i = wid + ii * 4;
        float ki0 = k_s[i][d0], ki1 = k_s[i][d0 + 1];
        float2 qv = *(const float2*)(Q + rowb + (size_t)i * 1024 + d0);
        float aa = wave_sum63(qv.x * ki0 + qv.y * ki1);
        if (lane == 63) Ao_s[i][i] = aa;           // diag: R = 1
        float R0 = 1.f, R1 = 1.f;
        for (int j = i - 1; j >= 0; --j) {
            R0 *= e_s[j + 1][d0]; R1 *= e_s[j + 1][d0 + 1];
            float u0 = R0 * k_s[j][d0], u1 = R1 * k_s[j][d0 + 1];
            float pp = wave_sum63(ki0 * u0 + ki1 * u1);
            float a2 = wave_sum63(qv.x * u0 + qv.y * u1);
            if (lane == 63) { P_s[i][j] = pp; Ao_s[i][j] = a2; }
        }
    }
    __syncthreads();

    // ---- phase 4: fold beta into strict-lower L ----
    for (int x = tid; x < 1024; x += 256) {
        int i2 = x >> 5, j2 = x & 31;
        P_s[i2][j2] = (j2 < i2) ? P_s[i2][j2] * beta_s[i2] : 0.f;
    }
    __syncthreads();

    // ---- phase 5: (I+L)W = b*Ktil (wave0), (I+L)U = b*V (wave1), Qtil ----
    if (wid == 0) {
        for (int i = 0; i < 32; ++i) {
            float bb = beta_s[i];
            float a0 = bb * k_s[i][d0] * (float)A_s[i][d0];
            float a1 = bb * k_s[i][d0 + 1] * (float)A_s[i][d0 + 1];
            for (int k2 = 0; k2 < i; ++k2) {
                float L = P_s[i][k2];
                a0 -= L * (float)W_s[k2][d0];
                a1 -= L * (float)W_s[k2][d0 + 1];
            }
            W_s[i][d0] = (hlf)a0; W_s[i][d0 + 1] = (hlf)a1;
        }
    } else if (wid == 1) {
        for (int i = 0; i < 32; ++i) {
            float bb = beta_s[i];
            float2 vv = *(const float2*)&U_s[i][d0];   // staged V (LDS)
            float a0 = bb * vv.x, a1 = bb * vv.y;
            for (int k2 = 0; k2 < i; ++k2) {
                float L = P_s[i][k2];
                a0 -= L * U_s[k2][d0];
                a1 -= L * U_s[k2][d0 + 1];
            }
            U_s[i][d0] = a0; U_s[i][d0 + 1] = a1;      // overwrite V with U
        }
    } else {
        for (int r2 = wid - 2; r2 < 32; r2 += 2) {
            float2 qv = *(const float2*)(Q + rowb + (size_t)r2 * 1024 + d0);
            Qt[co * 4096 + (size_t)r2 * 128 + d0]     = (hlf)(qv.x * (float)A_s[r2][d0]);
            Qt[co * 4096 + (size_t)r2 * 128 + d0 + 1] = (hlf)(qv.y * (float)A_s[r2][d0 + 1]);
        }
    }
    __syncthreads();

    // ---- phase 6: dumps ----
    for (int x = tid; x < 4096; x += 256) {
        Wn[co * 4096 + x] = (hlf)(-(float)W_s[x >> 7][x & 127]);
        Uf[co * 4096 + x] = U_s[x >> 7][x & 127];
    }
    for (int x = tid; x < 1024; x += 256)
        AoL[co * 1024 + x] = (hlf)Ao_s[x >> 5][x & 31];
}

// ---- pass 2: serial chunk scan. S in registers; global loads are volatile
// asm, DEPTH-2 rotation with a uniform robust wait: vmcnt(21) = "only the
// newest scan_load (21 ops) may remain in flight" -- completes everything
// older (the struct being consumed + any O-stores) regardless of compiler
// store placement. In-flight <= 46 < 63 HW cap; tied regs 2x72=144.
struct ScanOps {
    half8 aw0, aw1, aw2, aw3;
    half8 aq0, aq1, aq2, aq3;
    half8 bK0, bK1, bK2, bK3;
    half8 aA;
    float u0, u1, u2, u3;
    f32x4 ae0, ae1, ae2, ae3;
};

#define GLOAD16(dst, ptr) \
    asm volatile("global_load_dwordx4 %0, %1, off" : "=v"(dst) : "v"(ptr))
#define GLOAD4(dst, ptr) \
    asm volatile("global_load_dword %0, %1, off" : "=v"(dst) : "v"(ptr))

#define SCAN_WAIT21(o) \
    asm volatile("s_waitcnt vmcnt(21)" \
        : "+v"(o.aw0), "+v"(o.aw1), "+v"(o.aw2), "+v"(o.aw3), \
          "+v"(o.aq0), "+v"(o.aq1), "+v"(o.aq2), "+v"(o.aq3), \
          "+v"(o.aA), \
          "+v"(o.bK0), "+v"(o.bK1), "+v"(o.bK2), "+v"(o.bK3), \
          "+v"(o.u0), "+v"(o.u1), "+v"(o.u2), "+v"(o.u3), \
          "+v"(o.ae0), "+v"(o.ae1), "+v"(o.ae2), "+v"(o.ae3))

__device__ __forceinline__ void scan_load(ScanOps& o, size_t co,
    const hlf* __restrict__ Wn, const float* __restrict__ Uf,
    const hlf* __restrict__ Qt, const hlf* __restrict__ Ao,
    const hlf* __restrict__ KbT, const float* __restrict__ Aend,
    int tr, int vc, int dseg, int mq, int kq, int rq, int v0)
{
    const hlf*   Wc  = Wn  + co * 4096;
    const hlf*   Qc  = Qt  + co * 4096;
    const hlf*   Aoc = Ao  + co * 1024;
    const hlf*   Kbc = KbT + co * 4096;
    const float* Uc  = Uf  + co * 4096;
    const float* Aec = Aend + co * 128;
    size_t rw = (size_t)(tr + mq) * 128 + kq;
    GLOAD16(o.aw0, &Wc[rw]);
    GLOAD16(o.aw1, &Wc[rw + 32]);
    GLOAD16(o.aw2, &Wc[rw + 64]);
    GLOAD16(o.aw3, &Wc[rw + 96]);
    GLOAD16(o.aq0, &Qc[rw]);
    GLOAD16(o.aq1, &Qc[rw + 32]);
    GLOAD16(o.aq2, &Qc[rw + 64]);
    GLOAD16(o.aq3, &Qc[rw + 96]);
    GLOAD16(o.aA,  &Aoc[(tr + mq) * 32 + kq]);
    GLOAD16(o.bK0, &Kbc[(size_t)(dseg + mq) * 32 + kq]);
    GLOAD16(o.bK1, &Kbc[(size_t)(dseg + 16 + mq) * 32 + kq]);
    GLOAD16(o.bK2, &Kbc[(size_t)(dseg + 32 + mq) * 32 + kq]);
    GLOAD16(o.bK3, &Kbc[(size_t)(dseg + 48 + mq) * 32 + kq]);
    size_t ru = (size_t)(tr + rq) * 128 + v0 + vc + mq;
    GLOAD4(o.u0, &Uc[ru]);
    GLOAD4(o.u1, &Uc[ru + 128]);
    GLOAD4(o.u2, &Uc[ru + 256]);
    GLOAD4(o.u3, &Uc[ru + 384]);
    GLOAD16(o.ae0, &Aec[dseg + rq]);
    GLOAD16(o.ae1, &Aec[dseg + 16 + rq]);
    GLOAD16(o.ae2, &Aec[dseg + 32 + rq]);
    GLOAD16(o.ae3, &Aec[dseg + 48 + rq]);
}

__device__ __forceinline__ void scan_body(const ScanOps& o, int c,
    f32x4* sreg, hlf (*Sh)[136], hlf (*Dt)[40], float* __restrict__ O,
    int b, int h, int v0s, int T, int Mrows,
    int tr, int vc, int vtile, int dseg, int mq, int kq, int rq)
{
    // Sh reads (shared between Delta and O phases; held in regs across bar1)
    half8 bs0 = *(const half8*)&Sh[vc + mq][kq];
    half8 bs1 = *(const half8*)&Sh[vc + mq][32 + kq];
    half8 bs2 = *(const half8*)&Sh[vc + mq][64 + kq];
    half8 bs3 = *(const half8*)&Sh[vc + mq][96 + kq];

    // ---- Delta = U + (-W) @ S ----
    f32x4 dacc = {o.u0, o.u1, o.u2, o.u3};
    dacc = __builtin_amdgcn_mfma_f32_16x16x32_f16(o.aw0, bs0, dacc, 0, 0, 0);
    dacc = __builtin_amdgcn_mfma_f32_16x16x32_f16(o.aw1, bs1, dacc, 0, 0, 0);
    dacc = __builtin_amdgcn_mfma_f32_16x16x32_f16(o.aw2, bs2, dacc, 0, 0, 0);
    dacc = __builtin_amdgcn_mfma_f32_16x16x32_f16(o.aw3, bs3, dacc, 0, 0, 0);
    half4v dh4 = {(hlf)dacc[0], (hlf)dacc[1], (hlf)dacc[2], (hlf)dacc[3]};
    *(half4v*)&Dt[vc + mq][tr + rq] = dh4;

    asm volatile("s_waitcnt lgkmcnt(0)" ::: "memory");
    __builtin_amdgcn_s_barrier();
    __builtin_amdgcn_sched_barrier(0);

    // ---- O = Qtil @ S + Ao @ Delta ----
    f32x4 oacc = {0.f, 0.f, 0.f, 0.f};
    oacc = __builtin_amdgcn_mfma_f32_16x16x32_f16(o.aq0, bs0, oacc, 0, 0, 0);
    oacc = __builtin_amdgcn_mfma_f32_16x16x32_f16(o.aq1, bs1, oacc, 0, 0, 0);
    oacc = __builtin_amdgcn_mfma_f32_16x16x32_f16(o.aq2, bs2, oacc, 0, 0, 0);
    oacc = __builtin_amdgcn_mfma_f32_16x16x32_f16(o.aq3, bs3, oacc, 0, 0, 0);
    half8 bD = *(const half8*)&Dt[vc + mq][kq];
    oacc = __builtin_amdgcn_mfma_f32_16x16x32_f16(o.aA, bD, oacc, 0, 0, 0);
    // O split per v-slice: O4[vs][bt][h][32] -- no cross-XCD line sharing
    size_t ob = (size_t)v0s * Mrows * 256 +
                ((size_t)(b * T + c * 32 + tr + rq) * 8 + h) * 32 + vc + mq;
    O[ob]       = oacc[0];
    O[ob + 256] = oacc[1];
    O[ob + 512] = oacc[2];
    O[ob + 768] = oacc[3];

    // ---- S' = diag(Aend)*S + Kbar^T @ Delta, C[m=d][n=v] (register state) ----
    half8 aD = *(const half8*)&Dt[vtile + mq][kq];
    f32x4 s0 = sreg[0] * o.ae0;
    f32x4 s1 = sreg[1] * o.ae1;
    f32x4 s2 = sreg[2] * o.ae2;
    f32x4 s3 = sreg[3] * o.ae3;
    s0 = __builtin_amdgcn_mfma_f32_16x16x32_f16(o.bK0, aD, s0, 0, 0, 0);
    s1 = __builtin_amdgcn_mfma_f32_16x16x32_f16(o.bK1, aD, s1, 0, 0, 0);
    s2 = __builtin_amdgcn_mfma_f32_16x16x32_f16(o.bK2, aD, s2, 0, 0, 0);
    s3 = __builtin_amdgcn_mfma_f32_16x16x32_f16(o.bK3, aD, s3, 0, 0, 0);
    sreg[0] = s0; sreg[1] = s1; sreg[2] = s2; sreg[3] = s3;
    {   // f16 operand copy, vector half4 writes (4 consecutive d at fixed v)
        half4v h0 = {(hlf)s0[0], (hlf)s0[1], (hlf)s0[2], (hlf)s0[3]};
        half4v h1 = {(hlf)s1[0], (hlf)s1[1], (hlf)s1[2], (hlf)s1[3]};
        half4v h2 = {(hlf)s2[0], (hlf)s2[1], (hlf)s2[2], (hlf)s2[3]};
        half4v h3 = {(hlf)s3[0], (hlf)s3[1], (hlf)s3[2], (hlf)s3[3]};
        *(half4v*)&Sh[vtile + mq][dseg + rq]      = h0;
        *(half4v*)&Sh[vtile + mq][dseg + 16 + rq] = h1;
        *(half4v*)&Sh[vtile + mq][dseg + 32 + rq] = h2;
        *(half4v*)&Sh[vtile + mq][dseg + 48 + rq] = h3;
    }
    asm volatile("s_waitcnt lgkmcnt(0)" ::: "memory");
    __builtin_amdgcn_s_barrier();
    __builtin_amdgcn_sched_barrier(0);
}

// grid = nbh*4 (bh-major: the 4 v-splits of one bh land on the same XCD).
__global__ __launch_bounds__(256, 1) void chunk_scan_kernel(
    const hlf* __restrict__ Wn, const float* __restrict__ Uf,
    const hlf* __restrict__ Qt, const hlf* __restrict__ Ao,
    const hlf* __restrict__ KbT, const float* __restrict__ Aend,
    float* __restrict__ O, int T)
{
    __shared__ __align__(16) hlf  Sh[32][136];   // f16 S copy for MFMA B-reads
    __shared__ __align__(16) hlf  Dt[32][40];    // Delta^T [v][t] f16

    int tid = threadIdx.x, wid = tid >> 6, lane = tid & 63;
    int nbh = gridDim.x >> 2;
    int bh = blockIdx.x % nbh, vs = blockIdx.x / nbh;
    int b = bh >> 3, h = bh & 7;
    int v0 = vs * 32;
    int Mrows = (nbh >> 3) * T;

    for (int x = tid; x < 32 * 136; x += 256) ((hlf*)Sh)[x] = (hlf)0.f;

    int mq = lane & 15, kq = (lane >> 4) * 8, rq = (lane >> 4) * 4;
    int tr = (wid >> 1) * 16, vc = (wid & 1) * 16;      // Delta/O tile
    int vtile = (wid >> 1) * 16, dseg = (wid & 1) * 64; // S-update tiles

    f32x4 sreg[4] = {};   // S[d][v] register master (C[m=d][n=v] fragments)

    int NC = T / 32;
    size_t cb = (size_t)bh * 32;
    size_t comax = (size_t)nbh * 32 - 1;   // clamp for tail prefetches

    // barrier WITHOUT vmcnt drain (raw s_barrier; Sh init is DS -> lgkm only)
    asm volatile("s_waitcnt lgkmcnt(0)" ::: "memory");
    __builtin_amdgcn_s_barrier();

    ScanOps op0, op1;
    scan_load(op0, cb,     Wn, Uf, Qt, Ao, KbT, Aend, tr, vc, dseg, mq, kq, rq, v0);
    scan_load(op1, cb + 1, Wn, Uf, Qt, Ao, KbT, Aend, tr, vc, dseg, mq, kq, rq, v0);

#define CCLAMP(x) ((x) > comax ? comax : (x))
    for (int cc = 0; cc < NC; cc += 2) {
        SCAN_WAIT21(op0);
        scan_body(op0, cc, sreg, Sh, Dt, O, b, h, vs, T, Mrows,
                  tr, vc, vtile, dseg, mq, kq, rq);
        scan_load(op0, CCLAMP(cb + cc + 2), Wn, Uf, Qt, Ao, KbT, Aend,
                  tr, vc, dseg, mq, kq, rq, v0);

        SCAN_WAIT21(op1);
        scan_body(op1, cc + 1, sreg, Sh, Dt, O, b, h, vs, T, Mrows,
                  tr, vc, vtile, dseg, mq, kq, rq);
        scan_load(op1, CCLAMP(cb + cc + 3), Wn, Uf, Qt, Ao, KbT, Aend,
                  tr, vc, dseg, mq, kq, rq, v0);
    }
#undef CCLAMP
}

// -------- out = rmsnorm(o)*w*sigmoid(gate) -> bf16 (for final MFMA GEMM) ----
// O is the 4-way v-split layout: O4[vs][bt][h][32]
__global__ __launch_bounds__(128) void outnorm_kernel(const float* __restrict__ O,
                                                      const float* __restrict__ GATE,
                                                      const float* __restrict__ w,
                                                      bhalf* __restrict__ Obf,
                                                      int Mrows)
{
    int bid = blockIdx.x;
    int d = threadIdx.x;
    size_t base = (size_t)bid * D;
    float y = O[(size_t)(d >> 5) * Mrows * 256 + (size_t)bid * 32 + (d & 31)];
    __shared__ float red[2];
    float ss = y * y;
#pragma unroll
    for (int s = 32; s > 0; s >>= 1) ss += __shfl_xor(ss, s, 64);
    if ((threadIdx.x & 63) == 0) red[threadIdx.x >> 6] = ss;
    __syncthreads();
    float tot = red[0] + red[1];
    float r = rsqrtf(tot * (1.f / D) + 1e-5f);
    float gz = GATE[base + d];
    float sg = 1.f / (1.f + expf(-gz));
    Obf[base + d] = (bhalf)(y * r * w[d] * sg);
}

extern "C" void kernel_launch(void* const* d_in, const int* in_sizes, int n_in,
                              void* d_out, int out_size, void* d_ws, size_t ws_size,
                              hipStream_t stream)
{
    const float* x       = (const float*)d_in[0];
    const float* Wq      = (const float*)d_in[1];
    const float* Wk      = (const float*)d_in[2];
    const float* Wv      = (const float*)d_in[3];
    const float* wq_conv = (const float*)d_in[4];
    const float* wk_conv = (const float*)d_in[5];
    const float* wv_conv = (const float*)d_in[6];
    const float* Wfa     = (const float*)d_in[7];
    const float* Wfb     = (const float*)d_in[8];
    const float* Wb      = (const float*)d_in[9];
    const float* Wga     = (const float*)d_in[10];
    const float* Wgb     = (const float*)d_in[11];
    const float* A_log   = (const float*)d_in[12];
    const float* dt_bias = (const float*)d_in[13];
    const float* o_norm_w= (const float*)d_in[14];
    const float* Wo      = (const float*)d_in[15];

    int BT = in_sizes[0] / HID;     // B*T
    int T = 1024;
    int B_ = BT / T;
    size_t M = (size_t)BT;
    size_t sz_big = M * HID;
    const int nW = HID * HID;       // 1M
    const int nS = D * HID;         // 131072
    const int NCAT = 3392;          // 3072 qkv | 256 fa/ga | 8 beta | 56 pad

    // ---- explicit workspace layout (no aliasing) ----
    float* fp = (float*)d_ws;
    float* QKVp = fp;               fp += 3 * sz_big;   // M x 3072 fused q|k|v
    float* Qc   = fp;               fp += sz_big;
    float* Kc   = fp;               fp += sz_big;
    float* Vc   = fp;               fp += sz_big;
    float* EGb  = fp;               fp += sz_big;
    float* GATE = fp;               fp += sz_big;
    float* Obuf = fp;               fp += sz_big;
    float* BETA = fp;               fp += M * H;
    bhalf* bp = (bhalf*)fp;
    bhalf* xb   = bp;               bp += sz_big;
    bhalf* Wcat = bp;               bp += (size_t)NCAT * HID;  // Wq|Wk|Wv|Wfa|Wga|Wb|pad
    bhalf* Wob  = bp;               bp += nW;
    bhalf* Wfbb = bp;               bp += nS;
    bhalf* Wgbb = bp;               bp += nS;
    bhalf* XAG  = bp;               bp += M * 256;          // M x 256: xa|xg
    bhalf* Obf  = bp;               bp += sz_big;

    dim3 blk(256);

    // casts (4 launches, vectorized x4)
    cast1<<<(int)((sz_big / 4 + 255) / 256), 256, 0, stream>>>(x, xb, (int)(sz_big / 4));
    cast4<<<dim3((nW / 4 + 255) / 256, 4), 256, 0, stream>>>(Wq, Wk, Wv, Wo,
        Wcat, Wcat + nW, Wcat + 2 * (size_t)nW, Wob, nW / 4);
    cast4<<<dim3((nS / 4 + 255) / 256, 4), 256, 0, stream>>>(Wfa, Wga, Wfb, Wgb,
        Wcat + 3 * (size_t)nW, Wcat + 3 * (size_t)nW + nS, Wfbb, Wgbb, nS / 4);
    cast1<<<(H * HID / 4 + 255) / 256, 256, 0, stream>>>(Wb,
        Wcat + 3 * (size_t)nW + 2 * (size_t)nS, H * HID / 4);

    // mega first-stage GEMM: [QKV | XA,XG | beta] = xb @ Wcat^T  (N=3392)
    gemm_bf16_nt<<<dim3(NCAT / 64, BT / 128), blk, 0, stream>>>(
        xb, Wcat, QKVp, BT, NCAT, HID, HID, HID, 3072, 3, nullptr, nullptr,
        nullptr, nullptr, nullptr, 0, XAG, BETA);

    // conv + silu (+norm) fused, one launch
    conv3_kernel<<<dim3(BT * H, 3), 128, 0, stream>>>(QKVp,
                                                      wq_conv, wk_conv, wv_conv,
                                                      Qc, Kc, Vc, T);

    // second stage batched (z=0: EGb w/ fused eg transform; z=1: GATE)
    gemm_bf16_nt<<<dim3(HID / 64, BT / 128, 2), blk, 0, stream>>>(
        XAG, Wfbb, EGb, BT, HID, D, 256, D, HID, 1, A_log, dt_bias,
        XAG + D, Wgbb, GATE, 0, nullptr, nullptr);

    // ---- chunked recurrence: QKVp (24MB) is dead after conv3; reuse it ----
    int nbh = B_ * 8;
    float* Uf   = QKVp;
    float* Aend = Uf + (size_t)nbh * 32 * 4096;
    hlf* Wn  = (hlf*)(Aend + (size_t)nbh * 32 * 128);
    hlf* Qt  = Wn  + (size_t)nbh * 32 * 4096;
    hlf* AoLp= Qt  + (size_t)nbh * 32 * 4096;
    hlf* KbT = AoLp + (size_t)nbh * 32 * 1024;

    chunk_prep_kernel<<<nbh * 32, 256, 0, stream>>>(Qc, Kc, Vc, EGb, BETA,
                                                    Wn, Uf, Qt, AoLp, KbT, Aend, T);
    chunk_scan_kernel<<<nbh * 4, 256, 0, stream>>>(Wn, Uf, Qt, AoLp, KbT, Aend,
                                                   Obuf, T);

    // output norm * gate -> bf16
    outnorm_kernel<<<BT * H, 128, 0, stream>>>(Obuf, GATE, o_norm_w, Obf, BT);

    // final projection (bf16 MFMA)
    gemm_bf16_nt<<<dim3(HID / 64, BT / 128), blk, 0, stream>>>(
        Obf, Wob, (float*)d_out, BT, HID, HID, HID, HID, HID, 0, nullptr, nullptr,
        nullptr, nullptr, nullptr, 0, nullptr, nullptr);
}

// Round 12
// 305.452 us; speedup vs baseline: 1.2111x; 1.0126x over previous
//
#include <hip/hip_runtime.h>
#include <hip/hip_bf16.h>
#include <math.h>

#define H 8
#define D 128
#define HID 1024
#define KCONV 4

typedef __bf16 bhalf;
typedef __bf16 bhalf4 __attribute__((ext_vector_type(4)));
typedef __bf16 bhalf8 __attribute__((ext_vector_type(8)));
typedef float f32x4 __attribute__((ext_vector_type(4)));
typedef _Float16 hlf;
typedef _Float16 half8 __attribute__((ext_vector_type(8)));
typedef _Float16 half4v __attribute__((ext_vector_type(4)));

// ---- async global->LDS (direct-to-shared DMA, bypasses VGPRs) ----
__device__ __forceinline__ void async16(const void* g, void* l) {
    __builtin_amdgcn_global_load_lds(
        (const __attribute__((address_space(1))) void*)g,
        (__attribute__((address_space(3))) void*)l, 16, 0, 0);
}

// ---------------- bf16 MFMA GEMM: C[M,N] = A[M,K]*B[N,K]^T ----------------
// 128x64 tile, BK=32, 256 threads (4 waves, 2x2), global_load_lds staging.
__global__ __launch_bounds__(256) void gemm_bf16_nt(const bhalf* A, const bhalf* B,
                                                    void* Cv,
                                                    int M, int N, int K,
                                                    int lda, int ldb, int ldc, int epi,
                                                    const float* __restrict__ A_log,
                                                    const float* __restrict__ dt_bias,
                                                    const bhalf* A2, const bhalf* B2,
                                                    void* C2, int epi2,
                                                    bhalf* __restrict__ pXAG,
                                                    float* __restrict__ pBETA)
{
    if (blockIdx.z) { A = A2; B = B2; Cv = C2; epi = epi2; }
    __shared__ __align__(16) bhalf As[128][32];   // 8 KB
    __shared__ __align__(16) bhalf Bs[64][32];    // 4 KB
    int tid = threadIdx.x;
    int wid = tid >> 6, lane = tid & 63;
    int rowBase = blockIdx.y * 128;
    int colBase = blockIdx.x * 64;
    int wm = wid >> 1, wn = wid & 1;

    f32x4 acc[4][2] = {};

    int r = lane >> 2;          // 16 rows per 1KB instr
    int cseg = lane & 3;        // 16B segment within 64B row

    for (int k0 = 0; k0 < K; k0 += 32) {
        __syncthreads();
#pragma unroll
        for (int s = 0; s < 3; ++s) {
            int j = wid * 3 + s;            // 12 instrs: 8 A + 4 B
            if (j < 8) {
                const bhalf* ga = A + (size_t)(rowBase + j * 16 + r) * lda + k0 + cseg * 8;
                async16(ga, &As[j * 16][0]);
            } else {
                int jb = j - 8;
                const bhalf* ga = B + (size_t)(colBase + jb * 16 + r) * ldb + k0 + cseg * 8;
                async16(ga, &Bs[jb * 16][0]);
            }
        }
        __syncthreads();
        int mq = lane & 15, kq = (lane >> 4) * 8;
        bhalf8 af[4], bfr[2];
#pragma unroll
        for (int mt = 0; mt < 4; ++mt)
            af[mt] = *(const bhalf8*)&As[wm * 64 + mt * 16 + mq][kq];
#pragma unroll
        for (int nt = 0; nt < 2; ++nt)
            bfr[nt] = *(const bhalf8*)&Bs[wn * 32 + nt * 16 + mq][kq];
#pragma unroll
        for (int mt = 0; mt < 4; ++mt)
#pragma unroll
            for (int nt = 0; nt < 2; ++nt)
                acc[mt][nt] = __builtin_amdgcn_mfma_f32_16x16x32_bf16(
                    af[mt], bfr[nt], acc[mt][nt], 0, 0, 0);
    }
    int rquad = (lane >> 4) * 4;
#pragma unroll
    for (int mt = 0; mt < 4; ++mt) {
        int m0 = rowBase + wm * 64 + mt * 16 + rquad;
#pragma unroll
        for (int nt = 0; nt < 2; ++nt) {
            int c = colBase + wn * 32 + (lane & 15) + nt * 16;
#pragma unroll
            for (int rr = 0; rr < 4; ++rr) {
                float val = acc[mt][nt][rr];
                int m = m0 + rr;
                if (epi == 0) {
                    ((float*)Cv)[(size_t)m * ldc + c] = val;
                } else if (epi == 1) {
                    int h = c >> 7, d = c & 127;
                    float z = val + dt_bias[h * D + d];
                    float sp = (z > 20.f) ? z : log1pf(expf(z));
                    ((float*)Cv)[(size_t)m * ldc + c] = expf(-expf(A_log[h]) * sp);
                } else if (epi == 2) {
                    ((bhalf*)Cv)[(size_t)m * ldc + c] = (bhalf)val;
                } else {
                    if (c < 3072) {
                        ((float*)Cv)[(size_t)m * 3072 + c] = val;
                    } else if (c < 3328) {
                        pXAG[(size_t)m * 256 + (c - 3072)] = (bhalf)val;
                    } else if (c < 3336) {
                        pBETA[(size_t)m * 8 + (c - 3328)] = 1.f / (1.f + expf(-val));
                    }
                }
            }
        }
    }
}

// ---------------- casts (vectorized, 4 elems/thread) ----------------
__global__ void cast1(const float* __restrict__ s, bhalf* __restrict__ d, int n4)
{
    int i = blockIdx.x * blockDim.x + threadIdx.x;
    if (i >= n4) return;
    float4 v = ((const float4*)s)[i];
    bhalf4 o = {(bhalf)v.x, (bhalf)v.y, (bhalf)v.z, (bhalf)v.w};
    ((bhalf4*)d)[i] = o;
}
__global__ void cast4(const float* __restrict__ s0, const float* __restrict__ s1,
                      const float* __restrict__ s2, const float* __restrict__ s3,
                      bhalf* __restrict__ d0, bhalf* __restrict__ d1,
                      bhalf* __restrict__ d2, bhalf* __restrict__ d3, int n4)
{
    int i = blockIdx.x * blockDim.x + threadIdx.x;
    if (i >= n4) return;
    int a = blockIdx.y;
    const float* s = (a == 0) ? s0 : (a == 1) ? s1 : (a == 2) ? s2 : s3;
    bhalf* d = (a == 0) ? d0 : (a == 1) ? d1 : (a == 2) ? d2 : d3;
    float4 v = ((const float4*)s)[i];
    bhalf4 o = {(bhalf)v.x, (bhalf)v.y, (bhalf)v.z, (bhalf)v.w};
    ((bhalf4*)d)[i] = o;
}

// ------- fused depthwise causal conv (K=4) + SiLU (+ rmsnorm*scale) --------
__global__ __launch_bounds__(128) void conv3_kernel(const float* __restrict__ QKV,
                                                    const float* __restrict__ wq,
                                                    const float* __restrict__ wk,
                                                    const float* __restrict__ wv,
                                                    float* __restrict__ Qc,
                                                    float* __restrict__ Kc,
                                                    float* __restrict__ Vc,
                                                    int T)
{
    int which = blockIdx.y;
    const float* w; float* out; int mode; float scale;
    if (which == 0)      { w = wq; out = Qc; mode = 1; scale = 1.0f / 128.0f; }
    else if (which == 1) { w = wk; out = Kc; mode = 1; scale = 0.08838834764831845f; }
    else                 { w = wv; out = Vc; mode = 0; scale = 1.f; }

    int bid = blockIdx.x;
    int h = bid % H;
    int t = (bid / H) % T;
    int b = bid / (H * T);
    int d = threadIdx.x;
    int c = h * D + d;
    const float* base = QKV + (size_t)b * T * 3072 + which * 1024 + c;
    float acc = 0.f;
#pragma unroll
    for (int j = 0; j < KCONV; ++j) {
        int tt = t - (KCONV - 1) + j;
        float xv = (tt >= 0) ? base[(size_t)tt * 3072] : 0.f;
        acc += xv * w[c * KCONV + j];
    }
    float y = acc / (1.f + expf(-acc));
    if (mode) {
        __shared__ float red[2];
        float ss = y * y;
#pragma unroll
        for (int s = 32; s > 0; s >>= 1) ss += __shfl_xor(ss, s, 64);
        if ((threadIdx.x & 63) == 0) red[threadIdx.x >> 6] = ss;
        __syncthreads();
        float tot = red[0] + red[1];
        float r = rsqrtf(tot * (1.f / D) + 1e-6f);
        y = y * r * scale;
    }
    out[(size_t)bid * D + d] = y;
}

// ---------------- DPP wave64 reduction ----------------
template <int CTRL>
__device__ __forceinline__ float dpp_add(float x) {
    int y = __builtin_amdgcn_update_dpp(0, __builtin_bit_cast(int, x),
                                        CTRL, 0xF, 0xF, false);
    return x + __builtin_bit_cast(float, y);
}
// after this chain the full-wave sum is valid in lane 63
__device__ __forceinline__ float wave_sum63(float x) {
    x = dpp_add<0x111>(x);   // row_shr:1
    x = dpp_add<0x112>(x);   // row_shr:2
    x = dpp_add<0x114>(x);   // row_shr:4
    x = dpp_add<0x118>(x);   // row_shr:8
    x = dpp_add<0x142>(x);   // row_bcast:15
    x = dpp_add<0x143>(x);   // row_bcast:31
    return x;
}

// =======================================================================
// Chunked gated-delta-rule (WY / UT-transform), chunk C = 32.
//   A_i[d]   = prod_{s<=i} e_s          suff_i[d]= prod_{s>i} e_s
//   R_ij[d]  = prod_{j<s<=i} e_s        (walked iteratively; all <=1)
//   P_ij  = sum_d k_i k_j R_ij  (i>j)   Ao_ij = sum_d q_i k_j R_ij (i>=j)
//   (I + diag(b) tril(P)) Delta = b*(V - Ktil S),  Ktil_i = k_i*A_i
//   O = Qtil S + tril(Ao) Delta;  S <- diag(A_end) S + Kbar^T Delta
// =======================================================================

// ---- pass 1: fully parallel per (bh, chunk). fp32 compute, f16 out. ----
// V staged through U_s (in-place read->overwrite) so phase 5's serial
// substitution chain never waits on HBM. LDS 72K -> 2 blocks/CU.
__global__ __launch_bounds__(256) void chunk_prep_kernel(
    const float* __restrict__ Q, const float* __restrict__ K,
    const float* __restrict__ V, const float* __restrict__ E,
    const float* __restrict__ BETA,
    hlf* __restrict__ Wn, float* __restrict__ Uf, hlf* __restrict__ Qt,
    hlf* __restrict__ AoL, hlf* __restrict__ KbT, float* __restrict__ Aend,
    int T)
{
    __shared__ __align__(16) float e_s[32][128];   // 16K
    __shared__ __align__(16) float k_s[32][128];   // 16K
    __shared__ __align__(16) float U_s[32][128];   // 16K (V staged, then U)
    __shared__ __align__(16) hlf  A_s[32][128];    // 8K
    __shared__ __align__(16) hlf  W_s[32][128];    // 8K
    __shared__ float P_s[32][32];                  // 4K (beta-folded L)
    __shared__ float Ao_s[32][32];                 // 4K
    __shared__ float beta_s[32];

    int tid = threadIdx.x, wid = tid >> 6, lane = tid & 63;
    int bid = blockIdx.x;
    int bh = bid >> 5, ch = bid & 31;
    int b = bh >> 3, h = bh & 7;
    int t0 = ch * 32;
    size_t rowb = (size_t)(b * T + t0) * 1024 + h * 128;
    size_t co = (size_t)bh * 32 + ch;

    // ---- stage e,k,v (32 rows x 512B each; 1 async16 covers 2 rows) ----
    int rs2 = lane >> 5, seg = (lane & 31) * 4;
#pragma unroll
    for (int p = wid * 4; p < wid * 4 + 4; ++p) {
        int row = p * 2 + rs2;
        async16(E + rowb + (size_t)row * 1024 + seg, &e_s[p * 2][0]);
        async16(K + rowb + (size_t)row * 1024 + seg, &k_s[p * 2][0]);
        async16(V + rowb + (size_t)row * 1024 + seg, &U_s[p * 2][0]);
    }
    __syncthreads();

    // ---- phase 2: zero Ao, beta, cumulative products ----
    for (int x = tid; x < 1024; x += 256) Ao_s[x >> 5][x & 31] = 0.f;
    if (wid == 2 && lane < 32)
        beta_s[lane] = BETA[(size_t)(b * T + t0 + lane) * 8 + h];
    int d0 = lane * 2;
    if (wid == 0) {             // forward cumprod -> A_s, A_end
        float a0 = 1.f, a1 = 1.f;
        for (int t = 0; t < 32; ++t) {
            a0 *= e_s[t][d0]; a1 *= e_s[t][d0 + 1];
            A_s[t][d0] = (hlf)a0; A_s[t][d0 + 1] = (hlf)a1;
        }
        Aend[co * 128 + d0] = a0; Aend[co * 128 + d0 + 1] = a1;
    } else if (wid == 1) {      // backward suffix -> Kbar^T [d][t]
        float s0 = 1.f, s1 = 1.f;
        for (int t = 31; t >= 0; --t) {
            KbT[co * 4096 + (size_t)d0 * 32 + t]       = (hlf)(k_s[t][d0] * s0);
            KbT[co * 4096 + (size_t)(d0 + 1) * 32 + t] = (hlf)(k_s[t][d0 + 1] * s1);
            s0 *= e_s[t][d0]; s1 *= e_s[t][d0 + 1];
        }
    }
    __syncthreads();

    // ---- phase 3: P / Ao pairwise-decay triangle walk ----
#pragma unroll
    for (int ii = 0; ii < 8; ++ii) {
        int i = wid + ii * 4;
        float ki0 = k_s[i][d0], ki1 = k_s[i][d0 + 1];
        float2 qv = *(const float2*)(Q + rowb + (size_t)i * 1024 + d0);
        float aa = wave_sum63(qv.x * ki0 + qv.y * ki1);
        if (lane == 63) Ao_s[i][i] = aa;           // diag: R = 1
        float R0 = 1.f, R1 = 1.f;
        for (int j = i - 1; j >= 0; --j) {
            R0 *= e_s[j + 1][d0]; R1 *= e_s[j + 1][d0 + 1];
            float u0 = R0 * k_s[j][d0], u1 = R1 * k_s[j][d0 + 1];
            float pp = wave_sum63(ki0 * u0 + ki1 * u1);
            float a2 = wave_sum63(qv.x * u0 + qv.y * u1);
            if (lane == 63) { P_s[i][j] = pp; Ao_s[i][j] = a2; }
        }
    }
    __syncthreads();

    // ---- phase 4: fold beta into strict-lower L ----
    for (int x = tid; x < 1024; x += 256) {
        int i2 = x >> 5, j2 = x & 31;
        P_s[i2][j2] = (j2 < i2) ? P_s[i2][j2] * beta_s[i2] : 0.f;
    }
    __syncthreads();

    // ---- phase 5: (I+L)W = b*Ktil (wave0), (I+L)U = b*V (wave1), Qtil ----
    if (wid == 0) {
        for (int i = 0; i < 32; ++i) {
            float bb = beta_s[i];
            float a0 = bb * k_s[i][d0] * (float)A_s[i][d0];
            float a1 = bb * k_s[i][d0 + 1] * (float)A_s[i][d0 + 1];
            for (int k2 = 0; k2 < i; ++k2) {
                float L = P_s[i][k2];
                a0 -= L * (float)W_s[k2][d0];
                a1 -= L * (float)W_s[k2][d0 + 1];
            }
            W_s[i][d0] = (hlf)a0; W_s[i][d0 + 1] = (hlf)a1;
        }
    } else if (wid == 1) {
        for (int i = 0; i < 32; ++i) {
            float bb = beta_s[i];
            float2 vv = *(const float2*)&U_s[i][d0];   // staged V (LDS)
            float a0 = bb * vv.x, a1 = bb * vv.y;
            for (int k2 = 0; k2 < i; ++k2) {
                float L = P_s[i][k2];
                a0 -= L * U_s[k2][d0];
                a1 -= L * U_s[k2][d0 + 1];
            }
            U_s[i][d0] = a0; U_s[i][d0 + 1] = a1;      // overwrite V with U
        }
    } else {
        for (int r2 = wid - 2; r2 < 32; r2 += 2) {
            float2 qv = *(const float2*)(Q + rowb + (size_t)r2 * 1024 + d0);
            Qt[co * 4096 + (size_t)r2 * 128 + d0]     = (hlf)(qv.x * (float)A_s[r2][d0]);
            Qt[co * 4096 + (size_t)r2 * 128 + d0 + 1] = (hlf)(qv.y * (float)A_s[r2][d0 + 1]);
        }
    }
    __syncthreads();

    // ---- phase 6: dumps ----
    for (int x = tid; x < 4096; x += 256) {
        Wn[co * 4096 + x] = (hlf)(-(float)W_s[x >> 7][x & 127]);
        Uf[co * 4096 + x] = U_s[x >> 7][x & 127];
    }
    for (int x = tid; x < 1024; x += 256)
        AoL[co * 1024 + x] = (hlf)Ao_s[x >> 5][x & 31];
}

// ---- pass 2: serial chunk scan, SINGLE-WAVE blocks (64 thr), ZERO barriers.
// Each block owns one (bh, 16-col v-slice). Register prefetch (depth-2) is
// limited to the Delta/O operands (80 tied VGPR/struct); the S-update
// operands (KbT 8KB + Aend) go through double-buffered LDS via async16
// (9 vm ops/chunk, zero VGPR). One robust wait per chunk: vmcnt(35) =
// "only the newest 26+9 group may remain" -> consumed struct + its LDS
// staging complete, older O-stores retired. No s_barrier anywhere.
struct ScanOpsA {
    half8 aw0, aw1, aw2, aw3, aw4, aw5, aw6, aw7;
    half8 aq0, aq1, aq2, aq3, aq4, aq5, aq6, aq7;
    half8 aA0, aA1;
    float u0, u1, u2, u3, u4, u5, u6, u7;
};

#define GLOAD16(dst, ptr) \
    asm volatile("global_load_dwordx4 %0, %1, off" : "=v"(dst) : "v"(ptr))
#define GLOAD4(dst, ptr) \
    asm volatile("global_load_dword %0, %1, off" : "=v"(dst) : "v"(ptr))

#define SCAN_WAIT35(o) \
    do { \
    asm volatile("s_waitcnt vmcnt(35)" \
        : "+v"(o.aw0), "+v"(o.aw1), "+v"(o.aw2), "+v"(o.aw3), \
          "+v"(o.aw4), "+v"(o.aw5), "+v"(o.aw6), "+v"(o.aw7), \
          "+v"(o.aq0), "+v"(o.aq1), "+v"(o.aq2), "+v"(o.aq3), \
          "+v"(o.aq4), "+v"(o.aq5), "+v"(o.aq6), "+v"(o.aq7) \
        :: "memory"); \
    asm volatile("" \
        : "+v"(o.aA0), "+v"(o.aA1), \
          "+v"(o.u0), "+v"(o.u1), "+v"(o.u2), "+v"(o.u3), \
          "+v"(o.u4), "+v"(o.u5), "+v"(o.u6), "+v"(o.u7)); \
    __builtin_amdgcn_sched_barrier(0); \
    } while (0)

__device__ __forceinline__ void scan_loadA(ScanOpsA& o, size_t co,
    const hlf* __restrict__ Wn, const float* __restrict__ Uf,
    const hlf* __restrict__ Qt, const hlf* __restrict__ Ao,
    int mq, int kq, int rq, int v0)
{
    const hlf*   Wc  = Wn + co * 4096;
    const hlf*   Qc  = Qt + co * 4096;
    const hlf*   Aoc = Ao + co * 1024;
    const float* Uc  = Uf + co * 4096;
    size_t rw0 = (size_t)mq * 128 + kq;
    size_t rw1 = (size_t)(16 + mq) * 128 + kq;
    GLOAD16(o.aw0, &Wc[rw0]);
    GLOAD16(o.aw1, &Wc[rw0 + 32]);
    GLOAD16(o.aw2, &Wc[rw0 + 64]);
    GLOAD16(o.aw3, &Wc[rw0 + 96]);
    GLOAD16(o.aw4, &Wc[rw1]);
    GLOAD16(o.aw5, &Wc[rw1 + 32]);
    GLOAD16(o.aw6, &Wc[rw1 + 64]);
    GLOAD16(o.aw7, &Wc[rw1 + 96]);
    GLOAD16(o.aq0, &Qc[rw0]);
    GLOAD16(o.aq1, &Qc[rw0 + 32]);
    GLOAD16(o.aq2, &Qc[rw0 + 64]);
    GLOAD16(o.aq3, &Qc[rw0 + 96]);
    GLOAD16(o.aq4, &Qc[rw1]);
    GLOAD16(o.aq5, &Qc[rw1 + 32]);
    GLOAD16(o.aq6, &Qc[rw1 + 64]);
    GLOAD16(o.aq7, &Qc[rw1 + 96]);
    GLOAD16(o.aA0, &Aoc[mq * 32 + kq]);
    GLOAD16(o.aA1, &Aoc[(16 + mq) * 32 + kq]);
    size_t ru0 = (size_t)rq * 128 + v0 + mq;
    size_t ru1 = (size_t)(16 + rq) * 128 + v0 + mq;
    GLOAD4(o.u0, &Uc[ru0]);
    GLOAD4(o.u1, &Uc[ru0 + 128]);
    GLOAD4(o.u2, &Uc[ru0 + 256]);
    GLOAD4(o.u3, &Uc[ru0 + 384]);
    GLOAD4(o.u4, &Uc[ru1]);
    GLOAD4(o.u5, &Uc[ru1 + 128]);
    GLOAD4(o.u6, &Uc[ru1 + 256]);
    GLOAD4(o.u7, &Uc[ru1 + 384]);
}

// stage KbT (8KB, 8 instrs) + Aend (1024B = this chunk + next, 1 instr)
__device__ __forceinline__ void scan_stage(size_t co,
    const hlf* __restrict__ KbT, const float* __restrict__ Aend,
    hlf* kbt_l, float* ae_l, int lane)
{
    const hlf* Kbc = KbT + co * 4096;
#pragma unroll
    for (int p = 0; p < 8; ++p)
        async16(Kbc + p * 512 + lane * 8, kbt_l + p * 512);
    async16(Aend + co * 128 + lane * 4, ae_l);
}

__device__ __forceinline__ void scan_body(const ScanOpsA& o,
    const hlf* kbt_l, const float* ae_l, int c,
    f32x4* sreg, half8* Sb, hlf (*Sh)[136], hlf (*Dt)[40],
    float* __restrict__ O, int b, int h, int vs, int T, int Mrows,
    int mq, int kq, int rq)
{
    // ---- Delta = (-W) @ S + U (S=Sb from prev chunk, in regs) ----
    f32x4 d0 = {0.f, 0.f, 0.f, 0.f}, d1 = {0.f, 0.f, 0.f, 0.f};
    d0 = __builtin_amdgcn_mfma_f32_16x16x32_f16(o.aw0, Sb[0], d0, 0, 0, 0);
    d0 = __builtin_amdgcn_mfma_f32_16x16x32_f16(o.aw1, Sb[1], d0, 0, 0, 0);
    d0 = __builtin_amdgcn_mfma_f32_16x16x32_f16(o.aw2, Sb[2], d0, 0, 0, 0);
    d0 = __builtin_amdgcn_mfma_f32_16x16x32_f16(o.aw3, Sb[3], d0, 0, 0, 0);
    d1 = __builtin_amdgcn_mfma_f32_16x16x32_f16(o.aw4, Sb[0], d1, 0, 0, 0);
    d1 = __builtin_amdgcn_mfma_f32_16x16x32_f16(o.aw5, Sb[1], d1, 0, 0, 0);
    d1 = __builtin_amdgcn_mfma_f32_16x16x32_f16(o.aw6, Sb[2], d1, 0, 0, 0);
    d1 = __builtin_amdgcn_mfma_f32_16x16x32_f16(o.aw7, Sb[3], d1, 0, 0, 0);
    d0[0] += o.u0; d0[1] += o.u1; d0[2] += o.u2; d0[3] += o.u3;
    d1[0] += o.u4; d1[1] += o.u5; d1[2] += o.u6; d1[3] += o.u7;
    half4v dh0 = {(hlf)d0[0], (hlf)d0[1], (hlf)d0[2], (hlf)d0[3]};
    half4v dh1 = {(hlf)d1[0], (hlf)d1[1], (hlf)d1[2], (hlf)d1[3]};
    *(half4v*)&Dt[mq][rq]      = dh0;    // t = rq+r      (tile 0)
    *(half4v*)&Dt[mq][16 + rq] = dh1;    // t = 16+rq+r   (tile 1)

    // ---- O partial: Qtil @ S (independent of Dt; hides the ds_write) ----
    f32x4 o0 = {0.f, 0.f, 0.f, 0.f}, o1 = {0.f, 0.f, 0.f, 0.f};
    o0 = __builtin_amdgcn_mfma_f32_16x16x32_f16(o.aq0, Sb[0], o0, 0, 0, 0);
    o0 = __builtin_amdgcn_mfma_f32_16x16x32_f16(o.aq1, Sb[1], o0, 0, 0, 0);
    o0 = __builtin_amdgcn_mfma_f32_16x16x32_f16(o.aq2, Sb[2], o0, 0, 0, 0);
    o0 = __builtin_amdgcn_mfma_f32_16x16x32_f16(o.aq3, Sb[3], o0, 0, 0, 0);
    o1 = __builtin_amdgcn_mfma_f32_16x16x32_f16(o.aq4, Sb[0], o1, 0, 0, 0);
    o1 = __builtin_amdgcn_mfma_f32_16x16x32_f16(o.aq5, Sb[1], o1, 0, 0, 0);
    o1 = __builtin_amdgcn_mfma_f32_16x16x32_f16(o.aq6, Sb[2], o1, 0, 0, 0);
    o1 = __builtin_amdgcn_mfma_f32_16x16x32_f16(o.aq7, Sb[3], o1, 0, 0, 0);

    asm volatile("s_waitcnt lgkmcnt(0)" ::: "memory");
    __builtin_amdgcn_sched_barrier(0);

    // ---- Delta as B-frag (k = t), single read serves O and S-update ----
    half8 Dtb = *(const half8*)&Dt[mq][kq];
    o0 = __builtin_amdgcn_mfma_f32_16x16x32_f16(o.aA0, Dtb, o0, 0, 0, 0);
    o1 = __builtin_amdgcn_mfma_f32_16x16x32_f16(o.aA1, Dtb, o1, 0, 0, 0);
    // O split per 16-col v-slice: O8[vs][bt][h][16]
    size_t ob = (size_t)vs * Mrows * 128 +
                ((size_t)(b * T + c * 32 + rq) * 8 + h) * 16 + mq;
    O[ob]       = o0[0];
    O[ob + 128] = o0[1];
    O[ob + 256] = o0[2];
    O[ob + 384] = o0[3];
    size_t ob1 = ob + 2048;   // +16 t-rows
    O[ob1]       = o1[0];
    O[ob1 + 128] = o1[1];
    O[ob1 + 256] = o1[2];
    O[ob1 + 384] = o1[3];

    // ---- S' = diag(Aend)*S + Kbar^T @ Delta (full 128d x 16v, in regs;
    //      Kbar/Aend read from staged LDS) ----
    half8 bk0 = *(const half8*)&kbt_l[(size_t)(mq) * 32 + kq];
    half8 bk1 = *(const half8*)&kbt_l[(size_t)(16 + mq) * 32 + kq];
    half8 bk2 = *(const half8*)&kbt_l[(size_t)(32 + mq) * 32 + kq];
    half8 bk3 = *(const half8*)&kbt_l[(size_t)(48 + mq) * 32 + kq];
    half8 bk4 = *(const half8*)&kbt_l[(size_t)(64 + mq) * 32 + kq];
    half8 bk5 = *(const half8*)&kbt_l[(size_t)(80 + mq) * 32 + kq];
    half8 bk6 = *(const half8*)&kbt_l[(size_t)(96 + mq) * 32 + kq];
    half8 bk7 = *(const half8*)&kbt_l[(size_t)(112 + mq) * 32 + kq];
    f32x4 ae0 = *(const f32x4*)&ae_l[rq];
    f32x4 ae1 = *(const f32x4*)&ae_l[16 + rq];
    f32x4 ae2 = *(const f32x4*)&ae_l[32 + rq];
    f32x4 ae3 = *(const f32x4*)&ae_l[48 + rq];
    f32x4 ae4 = *(const f32x4*)&ae_l[64 + rq];
    f32x4 ae5 = *(const f32x4*)&ae_l[80 + rq];
    f32x4 ae6 = *(const f32x4*)&ae_l[96 + rq];
    f32x4 ae7 = *(const f32x4*)&ae_l[112 + rq];
    f32x4 s0 = sreg[0] * ae0;
    f32x4 s1 = sreg[1] * ae1;
    f32x4 s2 = sreg[2] * ae2;
    f32x4 s3 = sreg[3] * ae3;
    f32x4 s4 = sreg[4] * ae4;
    f32x4 s5 = sreg[5] * ae5;
    f32x4 s6 = sreg[6] * ae6;
    f32x4 s7 = sreg[7] * ae7;
    s0 = __builtin_amdgcn_mfma_f32_16x16x32_f16(bk0, Dtb, s0, 0, 0, 0);
    s1 = __builtin_amdgcn_mfma_f32_16x16x32_f16(bk1, Dtb, s1, 0, 0, 0);
    s2 = __builtin_amdgcn_mfma_f32_16x16x32_f16(bk2, Dtb, s2, 0, 0, 0);
    s3 = __builtin_amdgcn_mfma_f32_16x16x32_f16(bk3, Dtb, s3, 0, 0, 0);
    s4 = __builtin_amdgcn_mfma_f32_16x16x32_f16(bk4, Dtb, s4, 0, 0, 0);
    s5 = __builtin_amdgcn_mfma_f32_16x16x32_f16(bk5, Dtb, s5, 0, 0, 0);
    s6 = __builtin_amdgcn_mfma_f32_16x16x32_f16(bk6, Dtb, s6, 0, 0, 0);
    s7 = __builtin_amdgcn_mfma_f32_16x16x32_f16(bk7, Dtb, s7, 0, 0, 0);
    sreg[0] = s0; sreg[1] = s1; sreg[2] = s2; sreg[3] = s3;
    sreg[4] = s4; sreg[5] = s5; sreg[6] = s6; sreg[7] = s7;
    {   // f16 copy of S' through wave-private LDS (C-frag -> B-frag relayout)
        half4v h0 = {(hlf)s0[0], (hlf)s0[1], (hlf)s0[2], (hlf)s0[3]};
        half4v h1 = {(hlf)s1[0], (hlf)s1[1], (hlf)s1[2], (hlf)s1[3]};
        half4v h2 = {(hlf)s2[0], (hlf)s2[1], (hlf)s2[2], (hlf)s2[3]};
        half4v h3 = {(hlf)s3[0], (hlf)s3[1], (hlf)s3[2], (hlf)s3[3]};
        half4v h4 = {(hlf)s4[0], (hlf)s4[1], (hlf)s4[2], (hlf)s4[3]};
        half4v h5 = {(hlf)s5[0], (hlf)s5[1], (hlf)s5[2], (hlf)s5[3]};
        half4v h6 = {(hlf)s6[0], (hlf)s6[1], (hlf)s6[2], (hlf)s6[3]};
        half4v h7 = {(hlf)s7[0], (hlf)s7[1], (hlf)s7[2], (hlf)s7[3]};
        *(half4v*)&Sh[mq][rq]        = h0;
        *(half4v*)&Sh[mq][16 + rq]   = h1;
        *(half4v*)&Sh[mq][32 + rq]   = h2;
        *(half4v*)&Sh[mq][48 + rq]   = h3;
        *(half4v*)&Sh[mq][64 + rq]   = h4;
        *(half4v*)&Sh[mq][80 + rq]   = h5;
        *(half4v*)&Sh[mq][96 + rq]   = h6;
        *(half4v*)&Sh[mq][112 + rq]  = h7;
    }
    asm volatile("s_waitcnt lgkmcnt(0)" ::: "memory");
    __builtin_amdgcn_sched_barrier(0);
    Sb[0] = *(const half8*)&Sh[mq][kq];
    Sb[1] = *(const half8*)&Sh[mq][32 + kq];
    Sb[2] = *(const half8*)&Sh[mq][64 + kq];
    Sb[3] = *(const half8*)&Sh[mq][96 + kq];
    asm volatile("s_waitcnt lgkmcnt(0)" ::: "memory");
    __builtin_amdgcn_sched_barrier(0);
}

// grid = nbh*8 (bh-major: the 8 v-slices of one bh land on the same XCD).
__global__ __launch_bounds__(64, 1) void chunk_scan_kernel(
    const hlf* __restrict__ Wn, const float* __restrict__ Uf,
    const hlf* __restrict__ Qt, const hlf* __restrict__ Ao,
    const hlf* __restrict__ KbT, const float* __restrict__ Aend,
    float* __restrict__ O, int T)
{
    __shared__ __align__(16) hlf  kbt_l[2][4096];   // 16 KB staged KbT
    __shared__ __align__(16) float ae_l[2][256];    // 2 KB staged Aend
    __shared__ __align__(16) hlf  Sh[16][136];      // wave-private relayout
    __shared__ __align__(16) hlf  Dt[16][40];

    int lane = threadIdx.x & 63;
    int nbh = gridDim.x >> 3;
    int bh = blockIdx.x % nbh, vs = blockIdx.x / nbh;
    int b = bh >> 3, h = bh & 7;
    int v0 = vs * 16;
    int Mrows = (nbh >> 3) * T;

    int mq = lane & 15, kq = (lane >> 4) * 8, rq = (lane >> 4) * 4;

    f32x4 sreg[8] = {};   // S[d][v] C-frags: d = 16*dt + rq + r, v = mq
    half8 Sb[4];
    half8 hz = {(hlf)0.f, (hlf)0.f, (hlf)0.f, (hlf)0.f,
                (hlf)0.f, (hlf)0.f, (hlf)0.f, (hlf)0.f};
    Sb[0] = hz; Sb[1] = hz; Sb[2] = hz; Sb[3] = hz;

    int NC = T / 32;
    size_t cb = (size_t)bh * 32;
    size_t comax = (size_t)nbh * 32 - 1;   // clamp for tail prefetches

    ScanOpsA op0, op1;
    scan_loadA(op0, cb, Wn, Uf, Qt, Ao, mq, kq, rq, v0);
    scan_stage(cb, KbT, Aend, &kbt_l[0][0], &ae_l[0][0], lane);
    scan_loadA(op1, cb + 1, Wn, Uf, Qt, Ao, mq, kq, rq, v0);
    scan_stage(cb + 1, KbT, Aend, &kbt_l[1][0], &ae_l[1][0], lane);

#define CCLAMP(x) ((x) > comax ? comax : (x))
    for (int cc = 0; cc < NC; cc += 2) {
        SCAN_WAIT35(op0);
        scan_body(op0, &kbt_l[0][0], &ae_l[0][0], cc, sreg, Sb, Sh, Dt, O,
                  b, h, vs, T, Mrows, mq, kq, rq);
        scan_loadA(op0, CCLAMP(cb + cc + 2), Wn, Uf, Qt, Ao, mq, kq, rq, v0);
        scan_stage(CCLAMP(cb + cc + 2), KbT, Aend,
                   &kbt_l[0][0], &ae_l[0][0], lane);

        SCAN_WAIT35(op1);
        scan_body(op1, &kbt_l[1][0], &ae_l[1][0], cc + 1, sreg, Sb, Sh, Dt, O,
                  b, h, vs, T, Mrows, mq, kq, rq);
        scan_loadA(op1, CCLAMP(cb + cc + 3), Wn, Uf, Qt, Ao, mq, kq, rq, v0);
        scan_stage(CCLAMP(cb + cc + 3), KbT, Aend,
                   &kbt_l[1][0], &ae_l[1][0], lane);
    }
#undef CCLAMP
}

// -------- out = rmsnorm(o)*w*sigmoid(gate) -> bf16 (for final MFMA GEMM) ----
// O is the 8-way v-split layout: O8[vs][bt][h][16]
__global__ __launch_bounds__(128) void outnorm_kernel(const float* __restrict__ O,
                                                      const float* __restrict__ GATE,
                                                      const float* __restrict__ w,
                                                      bhalf* __restrict__ Obf,
                                                      int Mrows)
{
    int bid = blockIdx.x;
    int d = threadIdx.x;
    size_t base = (size_t)bid * D;
    float y = O[(size_t)(d >> 4) * Mrows * 128 + (size_t)bid * 16 + (d & 15)];
    __shared__ float red[2];
    float ss = y * y;
#pragma unroll
    for (int s = 32; s > 0; s >>= 1) ss += __shfl_xor(ss, s, 64);
    if ((threadIdx.x & 63) == 0) red[threadIdx.x >> 6] = ss;
    __syncthreads();
    float tot = red[0] + red[1];
    float r = rsqrtf(tot * (1.f / D) + 1e-5f);
    float gz = GATE[base + d];
    float sg = 1.f / (1.f + expf(-gz));
    Obf[base + d] = (bhalf)(y * r * w[d] * sg);
}

extern "C" void kernel_launch(void* const* d_in, const int* in_sizes, int n_in,
                              void* d_out, int out_size, void* d_ws, size_t ws_size,
                              hipStream_t stream)
{
    const float* x       = (const float*)d_in[0];
    const float* Wq      = (const float*)d_in[1];
    const float* Wk      = (const float*)d_in[2];
    const float* Wv      = (const float*)d_in[3];
    const float* wq_conv = (const float*)d_in[4];
    const float* wk_conv = (const float*)d_in[5];
    const float* wv_conv = (const float*)d_in[6];
    const float* Wfa     = (const float*)d_in[7];
    const float* Wfb     = (const float*)d_in[8];
    const float* Wb      = (const float*)d_in[9];
    const float* Wga     = (const float*)d_in[10];
    const float* Wgb     = (const float*)d_in[11];
    const float* A_log   = (const float*)d_in[12];
    const float* dt_bias = (const float*)d_in[13];
    const float* o_norm_w= (const float*)d_in[14];
    const float* Wo      = (const float*)d_in[15];

    int BT = in_sizes[0] / HID;     // B*T
    int T = 1024;
    int B_ = BT / T;
    size_t M = (size_t)BT;
    size_t sz_big = M * HID;
    const int nW = HID * HID;       // 1M
    const int nS = D * HID;         // 131072
    const int NCAT = 3392;          // 3072 qkv | 256 fa/ga | 8 beta | 56 pad

    // ---- explicit workspace layout (no aliasing) ----
    float* fp = (float*)d_ws;
    float* QKVp = fp;               fp += 3 * sz_big;   // M x 3072 fused q|k|v
    float* Qc   = fp;               fp += sz_big;
    float* Kc   = fp;               fp += sz_big;
    float* Vc   = fp;               fp += sz_big;
    float* EGb  = fp;               fp += sz_big;
    float* GATE = fp;               fp += sz_big;
    float* Obuf = fp;               fp += sz_big;
    float* BETA = fp;               fp += M * H;
    bhalf* bp = (bhalf*)fp;
    bhalf* xb   = bp;               bp += sz_big;
    bhalf* Wcat = bp;               bp += (size_t)NCAT * HID;  // Wq|Wk|Wv|Wfa|Wga|Wb|pad
    bhalf* Wob  = bp;               bp += nW;
    bhalf* Wfbb = bp;               bp += nS;
    bhalf* Wgbb = bp;               bp += nS;
    bhalf* XAG  = bp;               bp += M * 256;          // M x 256: xa|xg
    bhalf* Obf  = bp;               bp += sz_big;

    dim3 blk(256);

    // casts (4 launches, vectorized x4)
    cast1<<<(int)((sz_big / 4 + 255) / 256), 256, 0, stream>>>(x, xb, (int)(sz_big / 4));
    cast4<<<dim3((nW / 4 + 255) / 256, 4), 256, 0, stream>>>(Wq, Wk, Wv, Wo,
        Wcat, Wcat + nW, Wcat + 2 * (size_t)nW, Wob, nW / 4);
    cast4<<<dim3((nS / 4 + 255) / 256, 4), 256, 0, stream>>>(Wfa, Wga, Wfb, Wgb,
        Wcat + 3 * (size_t)nW, Wcat + 3 * (size_t)nW + nS, Wfbb, Wgbb, nS / 4);
    cast1<<<(H * HID / 4 + 255) / 256, 256, 0, stream>>>(Wb,
        Wcat + 3 * (size_t)nW + 2 * (size_t)nS, H * HID / 4);

    // mega first-stage GEMM: [QKV | XA,XG | beta] = xb @ Wcat^T  (N=3392)
    gemm_bf16_nt<<<dim3(NCAT / 64, BT / 128), blk, 0, stream>>>(
        xb, Wcat, QKVp, BT, NCAT, HID, HID, HID, 3072, 3, nullptr, nullptr,
        nullptr, nullptr, nullptr, 0, XAG, BETA);

    // conv + silu (+norm) fused, one launch
    conv3_kernel<<<dim3(BT * H, 3), 128, 0, stream>>>(QKVp,
                                                      wq_conv, wk_conv, wv_conv,
                                                      Qc, Kc, Vc, T);

    // second stage batched (z=0: EGb w/ fused eg transform; z=1: GATE)
    gemm_bf16_nt<<<dim3(HID / 64, BT / 128, 2), blk, 0, stream>>>(
        XAG, Wfbb, EGb, BT, HID, D, 256, D, HID, 1, A_log, dt_bias,
        XAG + D, Wgbb, GATE, 0, nullptr, nullptr);

    // ---- chunked recurrence: QKVp (24MB) is dead after conv3; reuse it ----
    int nbh = B_ * 8;
    float* Uf   = QKVp;
    float* Aend = Uf + (size_t)nbh * 32 * 4096;
    hlf* Wn  = (hlf*)(Aend + (size_t)nbh * 32 * 128);
    hlf* Qt  = Wn  + (size_t)nbh * 32 * 4096;
    hlf* AoLp= Qt  + (size_t)nbh * 32 * 4096;
    hlf* KbT = AoLp + (size_t)nbh * 32 * 1024;

    chunk_prep_kernel<<<nbh * 32, 256, 0, stream>>>(Qc, Kc, Vc, EGb, BETA,
                                                    Wn, Uf, Qt, AoLp, KbT, Aend, T);
    chunk_scan_kernel<<<nbh * 8, 64, 0, stream>>>(Wn, Uf, Qt, AoLp, KbT, Aend,
                                                  Obuf, T);

    // output norm * gate -> bf16
    outnorm_kernel<<<BT * H, 128, 0, stream>>>(Obuf, GATE, o_norm_w, Obf, BT);

    // final projection (bf16 MFMA)
    gemm_bf16_nt<<<dim3(HID / 64, BT / 128), blk, 0, stream>>>(
        Obf, Wob, (float*)d_out, BT, HID, HID, HID, HID, HID, 0, nullptr, nullptr,
        nullptr, nullptr, nullptr, 0, nullptr, nullptr);
}